// Round 5
// baseline (546.838 us; speedup 1.0000x reference)
//
#include <hip/hip_runtime.h>
#include <hip/hip_bf16.h>

// SAGAN attention block: B=4, C=256, H=W=64 (N=4096).
// Round 5: k_attn rewritten on 32x32x16 MFMA with swapped QK (S^T = K*Q^T):
// 32 queries/wave (halves LDS traffic/query), softmax lane-local (in-lane tree
// + 1 permlane swap), P->A-frags in-register via v_cvt_pkrtz + permlane32_swap
// (T12, no P LDS round-trip), single-buffer 64KB LDS => 2 blocks/CU (TLP covers
// staging latency), key-split x4 + weighted merge, defer-max (T13), setprio (T5).

typedef short short8 __attribute__((ext_vector_type(8)));
typedef float f32x4 __attribute__((ext_vector_type(4)));
typedef float f32x16 __attribute__((ext_vector_type(16)));
typedef _Float16 f16x8 __attribute__((ext_vector_type(8)));
typedef unsigned short u16;
typedef unsigned int u32;

#define DEV static __device__ __forceinline__
#define MFMA(a, b, c)   __builtin_amdgcn_mfma_f32_16x16x32_bf16(a, b, c, 0, 0, 0)
#define MFMA16(a, b, c) __builtin_amdgcn_mfma_f32_16x16x32_f16(a, b, c, 0, 0, 0)
#define MFMA32(a, b, c) __builtin_amdgcn_mfma_f32_32x32x16_f16(a, b, c, 0, 0, 0)

DEV u16 b16(float x) {
    __hip_bfloat16 h = __float2bfloat16(x);
    return *reinterpret_cast<u16*>(&h);
}
DEV float f16f(u16 u) {
    union { unsigned int ui; float f; } c;
    c.ui = ((unsigned int)u) << 16;
    return c.f;
}
DEV u16 h16(float x) {
    union { _Float16 h; u16 u; } c;
    c.h = (_Float16)x;
    return c.u;
}
DEV short8 ld8(const u16* p) { return *reinterpret_cast<const short8*>(p); }
DEV f16x8 ldh8(const u16* p) { return *reinterpret_cast<const f16x8*>(p); }

DEV u32 cvtpk(float a, float b) {  // packed f16 (rtz): lo=a, hi=b
    u32 r;
    asm("v_cvt_pkrtz_f16_f32 %0, %1, %2" : "=v"(r) : "v"(a), "v"(b));
    return r;
}
DEV void pswap(u32& a, u32& b) {  // swap hi-32-lanes(a) <-> lo-32-lanes(b)
    asm volatile("v_permlane32_swap_b32 %0, %1" : "+v"(a), "+v"(b));
}

// async global->LDS, 16B per lane; dst is wave-uniform base, HW adds lane*16
DEV void gload16(const void* g, void* l) {
    __builtin_amdgcn_global_load_lds(
        (const __attribute__((address_space(1))) unsigned int*)g,
        (__attribute__((address_space(3))) unsigned int*)l, 16, 0, 0);
}

// ---- workspace byte offsets ----
constexpr size_t OFF_WFH = 0;         // 128K bf16 hi
constexpr size_t OFF_WFL = 131072;
constexpr size_t OFF_WGH = 262144;
constexpr size_t OFF_WGL = 393216;
constexpr size_t OFF_WHB = 524288;    // 128K bf16
constexpr size_t OFF_WVB = 655360;    // 128K fp16
constexpr size_t OFF_ML  = 786432;    // 512K f32 pairs (4 splits x 16384 x {m,l})
constexpr size_t OFF_F   = 1310720;   // 8M fp16 [m][c]   (K source)
constexpr size_t OFF_G   = OFF_F + 8388608;    // 8M fp16 [m][c]  (Q source)
constexpr size_t OFF_H   = OFF_G + 8388608;    // 8M fp16 [b][c][n] (V source)
constexpr size_t OFF_XTH = OFF_H + 8388608;    // bf16 [m][c], dead after conv_h
constexpr size_t OFF_XTL = OFF_XTH + 8388608;
constexpr size_t OFF_OP  = OFF_XTH;            // 32M fp16 (4 splits), aliases dead Xt
constexpr size_t OFF_OT  = OFF_F;              // 8M fp16, aliases dead F
// high-water mark = OFF_OP + 33554432 = 60,030,976 bytes (round-2-proven)

// ---------------- weight prep ----------------
__global__ __launch_bounds__(256) void k_prep_w(
    const float* __restrict__ Wf, const float* __restrict__ Wg,
    const float* __restrict__ Wh, const float* __restrict__ Wv,
    u16* WFH, u16* WFL, u16* WGH, u16* WGL, u16* WHB, u16* WVB) {
    int i = blockIdx.x * 256 + threadIdx.x;
    float fv = Wf[i];
    u16 fh = b16(fv);
    WFH[i] = fh;
    WFL[i] = b16(fv - f16f(fh));
    float gv = Wg[i];
    u16 gh = b16(gv);
    WGH[i] = gh;
    WGL[i] = b16(gv - f16f(gh));
    WHB[i] = b16(Wh[i]);
    WVB[i] = h16(Wv[i]);
}

// ---------------- x transpose + split ----------------
__global__ __launch_bounds__(256) void k_prep_x(const float* __restrict__ x, u16* XtH, u16* XtL) {
    __shared__ float lds[64][65];
    int bid = blockIdx.x;
    int b = bid >> 8, rem = bid & 255, ct = rem >> 6, nt = rem & 63;
    int tid = threadIdx.x;
    int tx = tid & 63, ty = tid >> 6;
    const float* src = x + ((size_t)(b * 256 + ct * 64)) * 4096 + nt * 64;
#pragma unroll
    for (int k = 0; k < 16; ++k) {
        int cl = ty * 16 + k;
        lds[cl][tx] = src[(size_t)cl * 4096 + tx];
    }
    __syncthreads();
    int nl = tid >> 2, cg = tid & 3;
    short8 h0, h1, l0, l1;
#pragma unroll
    for (int j = 0; j < 8; ++j) {
        float v = lds[cg * 16 + j][nl];
        u16 hb = b16(v);
        h0[j] = (short)hb;
        l0[j] = (short)b16(v - f16f(hb));
    }
#pragma unroll
    for (int j = 8; j < 16; ++j) {
        float v = lds[cg * 16 + j][nl];
        u16 hb = b16(v);
        h1[j - 8] = (short)hb;
        l1[j - 8] = (short)b16(v - f16f(hb));
    }
    size_t dst = ((size_t)(b * 4096 + nt * 64 + nl)) * 256 + ct * 64 + cg * 16;
    *reinterpret_cast<short8*>(XtH + dst) = h0;
    *reinterpret_cast<short8*>(XtH + dst + 8) = h1;
    *reinterpret_cast<short8*>(XtL + dst) = l0;
    *reinterpret_cast<short8*>(XtL + dst + 8) = l1;
}

// ---------------- conv f,g: 3-pass split-bf16 MFMA, fp16 out ----------------
__global__ __launch_bounds__(256) void k_conv_fg(
    const u16* __restrict__ XtH, const u16* __restrict__ XtL,
    const u16* __restrict__ WFH, const u16* __restrict__ WFL,
    const u16* __restrict__ WGH, const u16* __restrict__ WGL,
    const float* __restrict__ bf, const float* __restrict__ bg,
    u16* F, u16* G) {
    int bidm = blockIdx.x & 255, bido = blockIdx.x >> 8;
    int w = threadIdx.x >> 6, lane = threadIdx.x & 63, r = lane & 15, g = lane >> 4;
    int m0 = bidm * 64 + w * 16, o0 = bido * 64;
    f32x4 fa[4], ga[4];
#pragma unroll
    for (int i = 0; i < 4; ++i) { fa[i] = {0.f, 0.f, 0.f, 0.f}; ga[i] = {0.f, 0.f, 0.f, 0.f}; }
    const u16* arh = XtH + (size_t)(m0 + r) * 256;
    const u16* arl = XtL + (size_t)(m0 + r) * 256;
#pragma unroll
    for (int ks = 0; ks < 8; ++ks) {
        int k0 = ks * 32 + 8 * g;
        short8 ah = ld8(arh + k0);
        short8 al = ld8(arl + k0);
#pragma unroll
        for (int ot = 0; ot < 4; ++ot) {
            size_t wrow = (size_t)(o0 + ot * 16 + r) * 256 + k0;
            short8 wfh = ld8(WFH + wrow), wfl = ld8(WFL + wrow);
            short8 wgh = ld8(WGH + wrow), wgl = ld8(WGL + wrow);
            fa[ot] = MFMA(ah, wfh, fa[ot]);
            fa[ot] = MFMA(ah, wfl, fa[ot]);
            fa[ot] = MFMA(al, wfh, fa[ot]);
            ga[ot] = MFMA(ah, wgh, ga[ot]);
            ga[ot] = MFMA(ah, wgl, ga[ot]);
            ga[ot] = MFMA(al, wgh, ga[ot]);
        }
    }
#pragma unroll
    for (int ot = 0; ot < 4; ++ot) {
#pragma unroll
        for (int q = 0; q < 4; ++q) {
            int row = m0 + 4 * g + q;
            int col = o0 + ot * 16 + r;
            size_t idx = (size_t)row * 256 + col;
            F[idx] = h16(fa[ot][q] + bf[col]);
            G[idx] = h16(ga[ot][q] + bg[col]);
        }
    }
}

// ---------------- conv h: bf16 MFMA, fp16 out, layout [b][c][n] ----------------
__global__ __launch_bounds__(256) void k_conv_h(
    const u16* __restrict__ WHB, const u16* __restrict__ XtH,
    const float* __restrict__ bh, u16* Hb) {
    int bidn = blockIdx.x & 255, bido = blockIdx.x >> 8;
    int w = threadIdx.x >> 6, lane = threadIdx.x & 63, r = lane & 15, g = lane >> 4;
    int o0 = bido * 64 + w * 16, n0 = bidn * 64;
    f32x4 acc[4];
#pragma unroll
    for (int i = 0; i < 4; ++i) acc[i] = {0.f, 0.f, 0.f, 0.f};
    const u16* arow = WHB + (size_t)(o0 + r) * 256;
#pragma unroll
    for (int ks = 0; ks < 8; ++ks) {
        int k0 = ks * 32 + 8 * g;
        short8 a = ld8(arow + k0);
#pragma unroll
        for (int ntl = 0; ntl < 4; ++ntl) {
            short8 bb = ld8(XtH + (size_t)(n0 + ntl * 16 + r) * 256 + k0);
            acc[ntl] = MFMA(a, bb, acc[ntl]);
        }
    }
#pragma unroll
    for (int ntl = 0; ntl < 4; ++ntl) {
#pragma unroll
        for (int q = 0; q < 4; ++q) {
            int o = o0 + 4 * g + q;
            int nf = n0 + ntl * 16 + r;
            int bb = nf >> 12, n = nf & 4095;
            Hb[((size_t)(bb * 256 + o)) * 4096 + n] = h16(acc[ntl][q] + bh[o]);
        }
    }
}

// ---------------- flash attention: 32x32 swapped-QK, in-register P ----------------
DEV float vmax16(const f32x16& v) {
    float a0 = fmaxf(fmaxf(v[0], v[1]), fmaxf(v[2], v[3]));
    float a1 = fmaxf(fmaxf(v[4], v[5]), fmaxf(v[6], v[7]));
    float a2 = fmaxf(fmaxf(v[8], v[9]), fmaxf(v[10], v[11]));
    float a3 = fmaxf(fmaxf(v[12], v[13]), fmaxf(v[14], v[15]));
    return fmaxf(fmaxf(a0, a1), fmaxf(a2, a3));
}
DEV float vsum16(const f32x16& v) {
    float a0 = (v[0] + v[1]) + (v[2] + v[3]);
    float a1 = (v[4] + v[5]) + (v[6] + v[7]);
    float a2 = (v[8] + v[9]) + (v[10] + v[11]);
    float a3 = (v[12] + v[13]) + (v[14] + v[15]);
    return (a0 + a1) + (a2 + a3);
}

__global__ __launch_bounds__(256, 2) void k_attn(
    const u16* __restrict__ F, const u16* __restrict__ G,
    const u16* __restrict__ Hb, u16* __restrict__ OP, float* __restrict__ ML) {
    // K tile [64 keys][256 c] fp16, swizzled byte ^= (key&7)<<4. 32KB.
    // V tile [256 c][64 i]   fp16, swizzled byte ^= (c&7)<<4.   32KB.
    __shared__ u16 Kt[16384];
    __shared__ u16 Vt[16384];

    int bid = blockIdx.x;            // 512 = 8 xcd * 64
    int xcd = bid & 7, idx = bid >> 3;
    int ks = xcd >> 1, bp = xcd & 1; // XCD carries (key-quarter, batch-pair)
    int b = bp * 2 + (idx & 1);
    int qb = idx >> 1;               // 0..31
    int tid = threadIdx.x;
    int w = tid >> 6, lane = tid & 63;
    int q5 = lane & 31, hi = lane >> 5;
    int j0 = qb * 128 + w * 32;      // wave's 32 queries
    const float L2E = 1.4426950408889634f;

    // Q resident in registers as QK B-operand: lane holds column q5 of Q.
    f16x8 Qf[16];
    {
        const u16* qrow = G + (size_t)(b * 4096 + j0 + q5) * 256 + 8 * hi;
#pragma unroll
        for (int s = 0; s < 16; ++s) Qf[s] = ldh8(qrow + s * 16);
    }
    const f32x16 Z16 = {0,0,0,0,0,0,0,0,0,0,0,0,0,0,0,0};
    f32x16 O[8];
#pragma unroll
    for (int i = 0; i < 8; ++i) O[i] = Z16;
    float mreg = -1e30f, lreg = 0.f;

    const char* Fb  = (const char*)(F + (size_t)b * 4096 * 256);
    const char* Hbb = (const char*)(Hb + (size_t)b * 256 * 4096);

    // staging address components (dest linear, source pre-swizzled)
    int krow0 = w * 16 + hi;            // K dest row for t=0
    int kcp   = (lane & 31) * 16;       // K within-row byte
    int vbase = ((w * 64 + (lane >> 3)) << 13) + (((lane & 7) * 16) ^ (((lane >> 3) & 7) << 4));

#define STAGE(I0)                                                               \
    do {                                                                        \
        const char* kb_ = Fb + (size_t)(I0) * 512;                              \
        const char* vb_ = Hbb + (size_t)(I0) * 2;                               \
        _Pragma("unroll") for (int t = 0; t < 8; ++t) {                         \
            int row = krow0 + 2 * t;                                            \
            gload16(kb_ + row * 512 + (kcp ^ ((row & 7) << 4)),                 \
                    (char*)Kt + (w * 8 + t) * 1024);                            \
        }                                                                       \
        _Pragma("unroll") for (int t = 0; t < 8; ++t)                           \
            gload16(vb_ + vbase + t * 65536, (char*)Vt + (w * 8 + t) * 1024);   \
    } while (0)

    int i0beg = ks * 1024;
    STAGE(i0beg);  // prologue

    for (int it = 0; it < 16; ++it) {
        __syncthreads();  // drains vmcnt(0): tile ready

        // ---- QK^T swapped: D[key][q] = sum_c K[key][c] * Q[q][c] ----
        const char* Kl = (const char*)Kt;
        const char* Vl = (const char*)Vt;
        f32x16 s0 = Z16, s1 = Z16;
        {
            const char* kr0 = Kl + q5 * 512;       // A row = key = lane&31
            int sw = (q5 & 7) << 4;
            __builtin_amdgcn_s_setprio(1);
#pragma unroll
            for (int s = 0; s < 16; ++s) {
                int off = (s * 32 + 16 * hi) ^ sw;
                f16x8 ka0 = *reinterpret_cast<const f16x8*>(kr0 + off);
                f16x8 ka1 = *reinterpret_cast<const f16x8*>(kr0 + 32 * 512 + off);
                s0 = MFMA32(ka0, Qf[s], s0);
                s1 = MFMA32(ka1, Qf[s], s1);
            }
            __builtin_amdgcn_s_setprio(0);
        }

        // ---- softmax: row q = lane-local column; reduce = in-lane + xor32 ----
        float v = fmaxf(vmax16(s0), vmax16(s1));
        v = fmaxf(v, __shfl_xor(v, 32));
        float grow = v - mreg;
        if (__all(grow <= 8.0f)) {  // T13 defer-max: skip rescale
#pragma unroll
            for (int i = 0; i < 16; ++i) s0[i] = exp2f((s0[i] - mreg) * L2E);
#pragma unroll
            for (int i = 0; i < 16; ++i) s1[i] = exp2f((s1[i] - mreg) * L2E);
            float rs = vsum16(s0) + vsum16(s1);
            rs += __shfl_xor(rs, 32);
            lreg += rs;
        } else {
            float mn = fmaxf(mreg, v);
            float corr = exp2f((mreg - mn) * L2E);
            mreg = mn;
#pragma unroll
            for (int i = 0; i < 16; ++i) s0[i] = exp2f((s0[i] - mn) * L2E);
#pragma unroll
            for (int i = 0; i < 16; ++i) s1[i] = exp2f((s1[i] - mn) * L2E);
            float rs = vsum16(s0) + vsum16(s1);
            rs += __shfl_xor(rs, 32);
            lreg = lreg * corr + rs;
            float cq[16];
#pragma unroll
            for (int rg = 0; rg < 16; ++rg)
                cq[rg] = __shfl(corr, (rg & 3) + 8 * (rg >> 2) + 4 * hi, 64);
#pragma unroll
            for (int ct = 0; ct < 8; ++ct)
#pragma unroll
                for (int rg = 0; rg < 16; ++rg) O[ct][rg] *= cq[rg];
        }

        // ---- P -> A-frags in-register (T12): cvt_pk pairs + permlane32_swap ----
        union { u32 wd[16]; f16x8 fr[4]; } pu;
#pragma unroll
        for (int t = 0; t < 4; ++t) {
            const f32x16& sh = (t >= 2) ? s1 : s0;
            int b0 = (t & 1) * 8;
            u32 u0 = cvtpk(sh[b0 + 0], sh[b0 + 1]);
            u32 u1 = cvtpk(sh[b0 + 2], sh[b0 + 3]);
            u32 u2 = cvtpk(sh[b0 + 4], sh[b0 + 5]);
            u32 u3 = cvtpk(sh[b0 + 6], sh[b0 + 7]);
            pswap(u0, u2);
            pswap(u1, u3);
            pu.wd[t * 4 + 0] = u0;
            pu.wd[t * 4 + 1] = u1;
            pu.wd[t * 4 + 2] = u2;
            pu.wd[t * 4 + 3] = u3;
        }

        // ---- PV: O[q][c] += P[q][i] * V[i][c] ----
        {
            const char* vr = Vl + q5 * 128;        // B col = c = lane&31 (+32ct)
            int swv = (q5 & 7) << 4;
            __builtin_amdgcn_s_setprio(1);
#pragma unroll
            for (int ct = 0; ct < 8; ++ct) {
                const char* vrc = vr + ct * 32 * 128;
#pragma unroll
                for (int t = 0; t < 4; ++t) {
                    f16x8 vb = *reinterpret_cast<const f16x8*>(vrc + ((t * 32 + 16 * hi) ^ swv));
                    O[ct] = MFMA32(pu.fr[t], vb, O[ct]);
                }
            }
            __builtin_amdgcn_s_setprio(0);
        }

        __syncthreads();  // all waves done reading K/V
        if (it + 1 < 16) STAGE(i0beg + (it + 1) * 64);
    }
#undef STAGE

    // ---- store normalized partial O (fp16) + (m,l) ----
    float linv = 1.f / lreg;
    float iq[16];
#pragma unroll
    for (int rg = 0; rg < 16; ++rg)
        iq[rg] = __shfl(linv, (rg & 3) + 8 * (rg >> 2) + 4 * hi, 64);
    u16* opb = OP + ((size_t)ks * 16384 + b * 4096 + j0) * 256;
#pragma unroll
    for (int ct = 0; ct < 8; ++ct) {
#pragma unroll
        for (int rg = 0; rg < 16; ++rg) {
            int qr = (rg & 3) + 8 * (rg >> 2) + 4 * hi;
            opb[(size_t)qr * 256 + ct * 32 + q5] = h16(O[ct][rg] * iq[rg]);
        }
    }
    if (hi == 0) {
        size_t mi = ((size_t)ks * 16384 + b * 4096 + j0 + q5) * 2;
        ML[mi] = mreg;
        ML[mi + 1] = lreg;
    }
}

// ---------------- merge key-splits (x4, normalized partials) -> OT fp16 [m][c] ----------------
__global__ __launch_bounds__(256) void k_merge(
    const u16* __restrict__ OP, const float* __restrict__ ML, u16* __restrict__ OT) {
    int t = blockIdx.x * 256 + threadIdx.x;  // 524288 threads
    int m = t >> 5;
    int c0 = (t & 31) * 8;
    const float L2E = 1.4426950408889634f;
    float mm[4], ll[4];
    float M = -1e30f;
#pragma unroll
    for (int ks = 0; ks < 4; ++ks) {
        size_t mi = ((size_t)ks * 16384 + m) * 2;
        mm[ks] = ML[mi];
        ll[ks] = ML[mi + 1];
        M = fmaxf(M, mm[ks]);
    }
    float wl[4], L = 0.f;
#pragma unroll
    for (int ks = 0; ks < 4; ++ks) {
        wl[ks] = exp2f((mm[ks] - M) * L2E) * ll[ks];
        L += wl[ks];
    }
    float inv = 1.f / L;
    float acc[8];
#pragma unroll
    for (int j = 0; j < 8; ++j) acc[j] = 0.f;
#pragma unroll
    for (int ks = 0; ks < 4; ++ks) {
        f16x8 v = ldh8(OP + ((size_t)ks * 16384 + m) * 256 + c0);
#pragma unroll
        for (int j = 0; j < 8; ++j) acc[j] += wl[ks] * (float)v[j];
    }
    short8 outp;
#pragma unroll
    for (int j = 0; j < 8; ++j) outp[j] = (short)h16(acc[j] * inv);
    *reinterpret_cast<short8*>(OT + (size_t)m * 256 + c0) = outp;
}

// ---------------- final conv: fp16 MFMA, f32 out ----------------
__global__ __launch_bounds__(256) void k_conv_out(
    const u16* __restrict__ WVB, const u16* __restrict__ OT,
    const float* __restrict__ bv, float* __restrict__ out) {
    int bidn = blockIdx.x & 255, bido = blockIdx.x >> 8;
    int w = threadIdx.x >> 6, lane = threadIdx.x & 63, r = lane & 15, g = lane >> 4;
    int o0 = bido * 64 + w * 16, n0 = bidn * 64;
    f32x4 acc[4];
#pragma unroll
    for (int i = 0; i < 4; ++i) acc[i] = {0.f, 0.f, 0.f, 0.f};
    const u16* arow = WVB + (size_t)(o0 + r) * 256;
#pragma unroll
    for (int ks = 0; ks < 8; ++ks) {
        int k0 = ks * 32 + 8 * g;
        f16x8 a = ldh8(arow + k0);
#pragma unroll
        for (int ntl = 0; ntl < 4; ++ntl) {
            f16x8 bb = ldh8(OT + (size_t)(n0 + ntl * 16 + r) * 256 + k0);
            acc[ntl] = MFMA16(a, bb, acc[ntl]);
        }
    }
#pragma unroll
    for (int ntl = 0; ntl < 4; ++ntl) {
#pragma unroll
        for (int q = 0; q < 4; ++q) {
            int o = o0 + 4 * g + q;
            int nf = n0 + ntl * 16 + r;
            int bb = nf >> 12, n = nf & 4095;
            out[((size_t)(bb * 256 + o)) * 4096 + n] = acc[ntl][q] + bv[o];
        }
    }
}

extern "C" void kernel_launch(void* const* d_in, const int* in_sizes, int n_in,
                              void* d_out, int out_size, void* d_ws, size_t ws_size,
                              hipStream_t stream) {
    const float* x  = (const float*)d_in[0];
    const float* Wf = (const float*)d_in[1];
    const float* bf = (const float*)d_in[2];
    const float* Wg = (const float*)d_in[3];
    const float* bg = (const float*)d_in[4];
    const float* Wh = (const float*)d_in[5];
    const float* bh = (const float*)d_in[6];
    const float* Wv = (const float*)d_in[7];
    const float* bv = (const float*)d_in[8];
    float* out = (float*)d_out;
    char* ws = (char*)d_ws;

    u16* WFH = (u16*)(ws + OFF_WFH);
    u16* WFL = (u16*)(ws + OFF_WFL);
    u16* WGH = (u16*)(ws + OFF_WGH);
    u16* WGL = (u16*)(ws + OFF_WGL);
    u16* WHB = (u16*)(ws + OFF_WHB);
    u16* WVB = (u16*)(ws + OFF_WVB);
    float* ML = (float*)(ws + OFF_ML);
    u16* F   = (u16*)(ws + OFF_F);
    u16* G   = (u16*)(ws + OFF_G);
    u16* H   = (u16*)(ws + OFF_H);
    u16* XTH = (u16*)(ws + OFF_XTH);
    u16* XTL = (u16*)(ws + OFF_XTL);
    u16* OP  = (u16*)(ws + OFF_OP);   // aliases Xt (dead after convs)
    u16* OT  = (u16*)(ws + OFF_OT);   // aliases F (dead after attn)

    k_prep_w<<<256, 256, 0, stream>>>(Wf, Wg, Wh, Wv, WFH, WFL, WGH, WGL, WHB, WVB);
    k_prep_x<<<1024, 256, 0, stream>>>(x, XTH, XTL);
    k_conv_fg<<<1024, 256, 0, stream>>>(XTH, XTL, WFH, WFL, WGH, WGL, bf, bg, F, G);
    k_conv_h<<<1024, 256, 0, stream>>>(WHB, XTH, bh, H);
    k_attn<<<512, 256, 0, stream>>>(F, G, H, OP, ML);
    k_merge<<<2048, 256, 0, stream>>>(OP, ML, OT);
    k_conv_out<<<1024, 256, 0, stream>>>(WVB, OT, bv, out);
}

// Round 6
// 328.421 us; speedup vs baseline: 1.6651x; 1.6651x over previous
//
#include <hip/hip_runtime.h>
#include <hip/hip_bf16.h>

// SAGAN attention block: B=4, C=256, H=W=64 (N=4096).
// Round 6: r5's 32x32 swapped-QK attention with the register footprint fixed:
// channel-split wave pairs (each wave: same 32 queries, half the PV channels,
// duplicated QK) -> ~210 VGPR, no launch_bounds cap (r5's (256,2) forced a
// 128-reg cap -> 918MB scratch spill traffic). 2 blocks/CU via 64KB LDS +
// <=256 VGPR. Key-split x2 + weighted merge. In-register P (cvt_pk+permlane),
// lane-local softmax, defer-max (T13), setprio (T5).

typedef short short8 __attribute__((ext_vector_type(8)));
typedef float f32x4 __attribute__((ext_vector_type(4)));
typedef float f32x16 __attribute__((ext_vector_type(16)));
typedef _Float16 f16x8 __attribute__((ext_vector_type(8)));
typedef unsigned short u16;
typedef unsigned int u32;

#define DEV static __device__ __forceinline__
#define MFMA(a, b, c)   __builtin_amdgcn_mfma_f32_16x16x32_bf16(a, b, c, 0, 0, 0)
#define MFMA16(a, b, c) __builtin_amdgcn_mfma_f32_16x16x32_f16(a, b, c, 0, 0, 0)
#define MFMA32(a, b, c) __builtin_amdgcn_mfma_f32_32x32x16_f16(a, b, c, 0, 0, 0)

DEV u16 b16(float x) {
    __hip_bfloat16 h = __float2bfloat16(x);
    return *reinterpret_cast<u16*>(&h);
}
DEV float f16f(u16 u) {
    union { unsigned int ui; float f; } c;
    c.ui = ((unsigned int)u) << 16;
    return c.f;
}
DEV u16 h16(float x) {
    union { _Float16 h; u16 u; } c;
    c.h = (_Float16)x;
    return c.u;
}
DEV short8 ld8(const u16* p) { return *reinterpret_cast<const short8*>(p); }
DEV f16x8 ldh8(const u16* p) { return *reinterpret_cast<const f16x8*>(p); }

DEV u32 cvtpk(float a, float b) {  // packed f16 (rtz): lo=a, hi=b
    u32 r;
    asm("v_cvt_pkrtz_f16_f32 %0, %1, %2" : "=v"(r) : "v"(a), "v"(b));
    return r;
}
DEV void pswap(u32& a, u32& b) {  // swap hi-32-lanes(a) <-> lo-32-lanes(b)
    asm volatile("v_permlane32_swap_b32 %0, %1" : "+v"(a), "+v"(b));
}

// async global->LDS, 16B per lane; dst is wave-uniform base, HW adds lane*16
DEV void gload16(const void* g, void* l) {
    __builtin_amdgcn_global_load_lds(
        (const __attribute__((address_space(1))) unsigned int*)g,
        (__attribute__((address_space(3))) unsigned int*)l, 16, 0, 0);
}

// ---- workspace byte offsets ----
constexpr size_t OFF_WFH = 0;         // 128K bf16 hi
constexpr size_t OFF_WFL = 131072;
constexpr size_t OFF_WGH = 262144;
constexpr size_t OFF_WGL = 393216;
constexpr size_t OFF_WHB = 524288;    // 128K bf16
constexpr size_t OFF_WVB = 655360;    // 128K fp16
constexpr size_t OFF_ML  = 786432;    // 256K f32 pairs (2 splits x 16384 x {m,l})
constexpr size_t OFF_F   = 1310720;   // 8M fp16 [m][c]   (K source)
constexpr size_t OFF_G   = OFF_F + 8388608;    // 8M fp16 [m][c]  (Q source)
constexpr size_t OFF_H   = OFF_G + 8388608;    // 8M fp16 [b][c][n] (V source)
constexpr size_t OFF_XTH = OFF_H + 8388608;    // bf16 [m][c], dead after conv_h
constexpr size_t OFF_XTL = OFF_XTH + 8388608;
constexpr size_t OFF_OP  = OFF_XTH;            // 16M fp16 (2 splits), aliases dead Xt
constexpr size_t OFF_OT  = OFF_F;              // 8M fp16, aliases dead F
// high-water mark < 52 MB

// ---------------- weight prep ----------------
__global__ __launch_bounds__(256) void k_prep_w(
    const float* __restrict__ Wf, const float* __restrict__ Wg,
    const float* __restrict__ Wh, const float* __restrict__ Wv,
    u16* WFH, u16* WFL, u16* WGH, u16* WGL, u16* WHB, u16* WVB) {
    int i = blockIdx.x * 256 + threadIdx.x;
    float fv = Wf[i];
    u16 fh = b16(fv);
    WFH[i] = fh;
    WFL[i] = b16(fv - f16f(fh));
    float gv = Wg[i];
    u16 gh = b16(gv);
    WGH[i] = gh;
    WGL[i] = b16(gv - f16f(gh));
    WHB[i] = b16(Wh[i]);
    WVB[i] = h16(Wv[i]);
}

// ---------------- x transpose + split ----------------
__global__ __launch_bounds__(256) void k_prep_x(const float* __restrict__ x, u16* XtH, u16* XtL) {
    __shared__ float lds[64][65];
    int bid = blockIdx.x;
    int b = bid >> 8, rem = bid & 255, ct = rem >> 6, nt = rem & 63;
    int tid = threadIdx.x;
    int tx = tid & 63, ty = tid >> 6;
    const float* src = x + ((size_t)(b * 256 + ct * 64)) * 4096 + nt * 64;
#pragma unroll
    for (int k = 0; k < 16; ++k) {
        int cl = ty * 16 + k;
        lds[cl][tx] = src[(size_t)cl * 4096 + tx];
    }
    __syncthreads();
    int nl = tid >> 2, cg = tid & 3;
    short8 h0, h1, l0, l1;
#pragma unroll
    for (int j = 0; j < 8; ++j) {
        float v = lds[cg * 16 + j][nl];
        u16 hb = b16(v);
        h0[j] = (short)hb;
        l0[j] = (short)b16(v - f16f(hb));
    }
#pragma unroll
    for (int j = 8; j < 16; ++j) {
        float v = lds[cg * 16 + j][nl];
        u16 hb = b16(v);
        h1[j - 8] = (short)hb;
        l1[j - 8] = (short)b16(v - f16f(hb));
    }
    size_t dst = ((size_t)(b * 4096 + nt * 64 + nl)) * 256 + ct * 64 + cg * 16;
    *reinterpret_cast<short8*>(XtH + dst) = h0;
    *reinterpret_cast<short8*>(XtH + dst + 8) = h1;
    *reinterpret_cast<short8*>(XtL + dst) = l0;
    *reinterpret_cast<short8*>(XtL + dst + 8) = l1;
}

// ---------------- conv f,g: 3-pass split-bf16 MFMA, fp16 out ----------------
__global__ __launch_bounds__(256) void k_conv_fg(
    const u16* __restrict__ XtH, const u16* __restrict__ XtL,
    const u16* __restrict__ WFH, const u16* __restrict__ WFL,
    const u16* __restrict__ WGH, const u16* __restrict__ WGL,
    const float* __restrict__ bf, const float* __restrict__ bg,
    u16* F, u16* G) {
    int bidm = blockIdx.x & 255, bido = blockIdx.x >> 8;
    int w = threadIdx.x >> 6, lane = threadIdx.x & 63, r = lane & 15, g = lane >> 4;
    int m0 = bidm * 64 + w * 16, o0 = bido * 64;
    f32x4 fa[4], ga[4];
#pragma unroll
    for (int i = 0; i < 4; ++i) { fa[i] = {0.f, 0.f, 0.f, 0.f}; ga[i] = {0.f, 0.f, 0.f, 0.f}; }
    const u16* arh = XtH + (size_t)(m0 + r) * 256;
    const u16* arl = XtL + (size_t)(m0 + r) * 256;
#pragma unroll
    for (int ks = 0; ks < 8; ++ks) {
        int k0 = ks * 32 + 8 * g;
        short8 ah = ld8(arh + k0);
        short8 al = ld8(arl + k0);
#pragma unroll
        for (int ot = 0; ot < 4; ++ot) {
            size_t wrow = (size_t)(o0 + ot * 16 + r) * 256 + k0;
            short8 wfh = ld8(WFH + wrow), wfl = ld8(WFL + wrow);
            short8 wgh = ld8(WGH + wrow), wgl = ld8(WGL + wrow);
            fa[ot] = MFMA(ah, wfh, fa[ot]);
            fa[ot] = MFMA(ah, wfl, fa[ot]);
            fa[ot] = MFMA(al, wfh, fa[ot]);
            ga[ot] = MFMA(ah, wgh, ga[ot]);
            ga[ot] = MFMA(ah, wgl, ga[ot]);
            ga[ot] = MFMA(al, wgh, ga[ot]);
        }
    }
#pragma unroll
    for (int ot = 0; ot < 4; ++ot) {
#pragma unroll
        for (int q = 0; q < 4; ++q) {
            int row = m0 + 4 * g + q;
            int col = o0 + ot * 16 + r;
            size_t idx = (size_t)row * 256 + col;
            F[idx] = h16(fa[ot][q] + bf[col]);
            G[idx] = h16(ga[ot][q] + bg[col]);
        }
    }
}

// ---------------- conv h: bf16 MFMA, fp16 out, layout [b][c][n] ----------------
__global__ __launch_bounds__(256) void k_conv_h(
    const u16* __restrict__ WHB, const u16* __restrict__ XtH,
    const float* __restrict__ bh, u16* Hb) {
    int bidn = blockIdx.x & 255, bido = blockIdx.x >> 8;
    int w = threadIdx.x >> 6, lane = threadIdx.x & 63, r = lane & 15, g = lane >> 4;
    int o0 = bido * 64 + w * 16, n0 = bidn * 64;
    f32x4 acc[4];
#pragma unroll
    for (int i = 0; i < 4; ++i) acc[i] = {0.f, 0.f, 0.f, 0.f};
    const u16* arow = WHB + (size_t)(o0 + r) * 256;
#pragma unroll
    for (int ks = 0; ks < 8; ++ks) {
        int k0 = ks * 32 + 8 * g;
        short8 a = ld8(arow + k0);
#pragma unroll
        for (int ntl = 0; ntl < 4; ++ntl) {
            short8 bb = ld8(XtH + (size_t)(n0 + ntl * 16 + r) * 256 + k0);
            acc[ntl] = MFMA(a, bb, acc[ntl]);
        }
    }
#pragma unroll
    for (int ntl = 0; ntl < 4; ++ntl) {
#pragma unroll
        for (int q = 0; q < 4; ++q) {
            int o = o0 + 4 * g + q;
            int nf = n0 + ntl * 16 + r;
            int bb = nf >> 12, n = nf & 4095;
            Hb[((size_t)(bb * 256 + o)) * 4096 + n] = h16(acc[ntl][q] + bh[o]);
        }
    }
}

// ---------------- flash attention: 32x32 swapped-QK, channel-split wave pairs ----------------
DEV float vmax16(const f32x16& v) {
    float a0 = fmaxf(fmaxf(v[0], v[1]), fmaxf(v[2], v[3]));
    float a1 = fmaxf(fmaxf(v[4], v[5]), fmaxf(v[6], v[7]));
    float a2 = fmaxf(fmaxf(v[8], v[9]), fmaxf(v[10], v[11]));
    float a3 = fmaxf(fmaxf(v[12], v[13]), fmaxf(v[14], v[15]));
    return fmaxf(fmaxf(a0, a1), fmaxf(a2, a3));
}
DEV float vsum16(const f32x16& v) {
    float a0 = (v[0] + v[1]) + (v[2] + v[3]);
    float a1 = (v[4] + v[5]) + (v[6] + v[7]);
    float a2 = (v[8] + v[9]) + (v[10] + v[11]);
    float a3 = (v[12] + v[13]) + (v[14] + v[15]);
    return (a0 + a1) + (a2 + a3);
}

__global__ __launch_bounds__(256) void k_attn(
    const u16* __restrict__ F, const u16* __restrict__ G,
    const u16* __restrict__ Hb, u16* __restrict__ OP, float* __restrict__ ML) {
    // K tile [64 keys][256 c] fp16, swizzled byte ^= (key&7)<<4. 32KB.
    // V tile [256 c][64 i]   fp16, swizzled byte ^= (c&7)<<4.   32KB.
    __shared__ u16 Kt[16384];
    __shared__ u16 Vt[16384];

    int bid = blockIdx.x;            // 512 = 8 xcd * 64
    int xcd = bid & 7, idx = bid >> 3;
    int b = xcd >> 1, ks = xcd & 1;  // XCD carries (batch, key-half)
    int tid = threadIdx.x;
    int w = tid >> 6, lane = tid & 63;
    int qg = w >> 1, ch = w & 1;     // wave pair: same queries, split channels
    int q5 = lane & 31, hi = lane >> 5;
    int j0 = idx * 64 + qg * 32;     // wave's 32 queries
    const float L2E = 1.4426950408889634f;

    // Q resident in registers as QK B-operand: lane holds column q5 of Q.
    f16x8 Qf[16];
    {
        const u16* qrow = G + (size_t)(b * 4096 + j0 + q5) * 256 + 8 * hi;
#pragma unroll
        for (int s = 0; s < 16; ++s) Qf[s] = ldh8(qrow + s * 16);
    }
    const f32x16 Z16 = {0,0,0,0,0,0,0,0,0,0,0,0,0,0,0,0};
    f32x16 O[4];                     // 32 q x 128 c (this wave's channel half)
#pragma unroll
    for (int i = 0; i < 4; ++i) O[i] = Z16;
    float mreg = -1e30f, lreg = 0.f;

    const char* Fb  = (const char*)(F + (size_t)b * 4096 * 256);
    const char* Hbb = (const char*)(Hb + (size_t)b * 256 * 4096);

    // staging address components (dest linear, source pre-swizzled)
    int krow0 = w * 16 + hi;            // K dest row for t=0
    int kcp   = (lane & 31) * 16;       // K within-row byte
    int vbase = ((w * 64 + (lane >> 3)) << 13) + (((lane & 7) * 16) ^ (((lane >> 3) & 7) << 4));

#define STAGE(I0)                                                               \
    do {                                                                        \
        const char* kb_ = Fb + (size_t)(I0) * 512;                              \
        const char* vb_ = Hbb + (size_t)(I0) * 2;                               \
        _Pragma("unroll") for (int t = 0; t < 8; ++t) {                         \
            int row = krow0 + 2 * t;                                            \
            gload16(kb_ + row * 512 + (kcp ^ ((row & 7) << 4)),                 \
                    (char*)Kt + (w * 8 + t) * 1024);                            \
        }                                                                       \
        _Pragma("unroll") for (int t = 0; t < 8; ++t)                           \
            gload16(vb_ + vbase + t * 65536, (char*)Vt + (w * 8 + t) * 1024);   \
    } while (0)

    int i0beg = ks * 2048;
    STAGE(i0beg);  // prologue

    for (int it = 0; it < 32; ++it) {
        __syncthreads();  // drains vmcnt(0): tile ready

        // ---- QK^T swapped: D[key][q] = sum_c K[key][c] * Q[q][c] ----
        const char* Kl = (const char*)Kt;
        const char* Vl = (const char*)Vt;
        f32x16 s0 = Z16, s1 = Z16;
        {
            const char* kr0 = Kl + q5 * 512;       // A row = key = lane&31
            int sw = (q5 & 7) << 4;
            __builtin_amdgcn_s_setprio(1);
#pragma unroll
            for (int s = 0; s < 16; ++s) {
                int off = (s * 32 + 16 * hi) ^ sw;
                f16x8 ka0 = *reinterpret_cast<const f16x8*>(kr0 + off);
                f16x8 ka1 = *reinterpret_cast<const f16x8*>(kr0 + 32 * 512 + off);
                s0 = MFMA32(ka0, Qf[s], s0);
                s1 = MFMA32(ka1, Qf[s], s1);
            }
            __builtin_amdgcn_s_setprio(0);
        }

        // ---- softmax: row q = lane-local column; reduce = in-lane + xor32 ----
        float v = fmaxf(vmax16(s0), vmax16(s1));
        v = fmaxf(v, __shfl_xor(v, 32));
        float grow = v - mreg;
        if (__all(grow <= 8.0f)) {  // T13 defer-max: skip rescale
#pragma unroll
            for (int i = 0; i < 16; ++i) s0[i] = exp2f((s0[i] - mreg) * L2E);
#pragma unroll
            for (int i = 0; i < 16; ++i) s1[i] = exp2f((s1[i] - mreg) * L2E);
            float rs = vsum16(s0) + vsum16(s1);
            rs += __shfl_xor(rs, 32);
            lreg += rs;
        } else {
            float mn = fmaxf(mreg, v);
            float corr = exp2f((mreg - mn) * L2E);
            mreg = mn;
#pragma unroll
            for (int i = 0; i < 16; ++i) s0[i] = exp2f((s0[i] - mn) * L2E);
#pragma unroll
            for (int i = 0; i < 16; ++i) s1[i] = exp2f((s1[i] - mn) * L2E);
            float rs = vsum16(s0) + vsum16(s1);
            rs += __shfl_xor(rs, 32);
            lreg = lreg * corr + rs;
            float cq[16];
#pragma unroll
            for (int rg = 0; rg < 16; ++rg)
                cq[rg] = __shfl(corr, (rg & 3) + 8 * (rg >> 2) + 4 * hi, 64);
#pragma unroll
            for (int ct = 0; ct < 4; ++ct)
#pragma unroll
                for (int rg = 0; rg < 16; ++rg) O[ct][rg] *= cq[rg];
        }

        // ---- P -> A-frags in-register (T12): cvt_pk pairs + permlane32_swap ----
        union { u32 wd[16]; f16x8 fr[4]; } pu;
#pragma unroll
        for (int t = 0; t < 4; ++t) {
            const f32x16& sh = (t >= 2) ? s1 : s0;
            int b0 = (t & 1) * 8;
            u32 u0 = cvtpk(sh[b0 + 0], sh[b0 + 1]);
            u32 u1 = cvtpk(sh[b0 + 2], sh[b0 + 3]);
            u32 u2 = cvtpk(sh[b0 + 4], sh[b0 + 5]);
            u32 u3 = cvtpk(sh[b0 + 6], sh[b0 + 7]);
            pswap(u0, u2);
            pswap(u1, u3);
            pu.wd[t * 4 + 0] = u0;
            pu.wd[t * 4 + 1] = u1;
            pu.wd[t * 4 + 2] = u2;
            pu.wd[t * 4 + 3] = u3;
        }

        // ---- PV (this wave's 128-channel half): O[q][c] += P[q][i] * V[i][c] ----
        {
            const char* vr = Vl + (ch * 128 + q5) * 128;  // B col = c
            int swv = (q5 & 7) << 4;
            __builtin_amdgcn_s_setprio(1);
#pragma unroll
            for (int ct = 0; ct < 4; ++ct) {
                const char* vrc = vr + ct * 32 * 128;
#pragma unroll
                for (int t = 0; t < 4; ++t) {
                    f16x8 vb = *reinterpret_cast<const f16x8*>(vrc + ((t * 32 + 16 * hi) ^ swv));
                    O[ct] = MFMA32(pu.fr[t], vb, O[ct]);
                }
            }
            __builtin_amdgcn_s_setprio(0);
        }

        __syncthreads();  // all waves done reading K/V
        if (it + 1 < 32) STAGE(i0beg + (it + 1) * 64);
    }
#undef STAGE

    // ---- store normalized partial O (fp16) + (m,l) ----
    float linv = 1.f / lreg;
    float iq[16];
#pragma unroll
    for (int rg = 0; rg < 16; ++rg)
        iq[rg] = __shfl(linv, (rg & 3) + 8 * (rg >> 2) + 4 * hi, 64);
    u16* opb = OP + ((size_t)ks * 16384 + b * 4096 + j0) * 256;
#pragma unroll
    for (int ct = 0; ct < 4; ++ct) {
#pragma unroll
        for (int rg = 0; rg < 16; ++rg) {
            int qr = (rg & 3) + 8 * (rg >> 2) + 4 * hi;
            opb[(size_t)qr * 256 + ch * 128 + ct * 32 + q5] = h16(O[ct][rg] * iq[rg]);
        }
    }
    if (ch == 0 && hi == 0) {
        size_t mi = ((size_t)ks * 16384 + b * 4096 + j0 + q5) * 2;
        ML[mi] = mreg;
        ML[mi + 1] = lreg;
    }
}

// ---------------- merge key-splits (x2, normalized partials) -> OT fp16 [m][c] ----------------
__global__ __launch_bounds__(256) void k_merge(
    const u16* __restrict__ OP, const float* __restrict__ ML, u16* __restrict__ OT) {
    int t = blockIdx.x * 256 + threadIdx.x;  // 524288 threads
    int m = t >> 5;
    int c0 = (t & 31) * 8;
    const float L2E = 1.4426950408889634f;
    float m0 = ML[(size_t)m * 2], l0 = ML[(size_t)m * 2 + 1];
    float m1 = ML[((size_t)16384 + m) * 2], l1 = ML[((size_t)16384 + m) * 2 + 1];
    float M = fmaxf(m0, m1);
    float wl0 = exp2f((m0 - M) * L2E) * l0;
    float wl1 = exp2f((m1 - M) * L2E) * l1;
    float inv = 1.f / (wl0 + wl1);
    f16x8 v0 = ldh8(OP + (size_t)m * 256 + c0);
    f16x8 v1 = ldh8(OP + ((size_t)16384 + m) * 256 + c0);
    short8 outp;
#pragma unroll
    for (int j = 0; j < 8; ++j)
        outp[j] = (short)h16((wl0 * (float)v0[j] + wl1 * (float)v1[j]) * inv);
    *reinterpret_cast<short8*>(OT + (size_t)m * 256 + c0) = outp;
}

// ---------------- final conv: fp16 MFMA, f32 out ----------------
__global__ __launch_bounds__(256) void k_conv_out(
    const u16* __restrict__ WVB, const u16* __restrict__ OT,
    const float* __restrict__ bv, float* __restrict__ out) {
    int bidn = blockIdx.x & 255, bido = blockIdx.x >> 8;
    int w = threadIdx.x >> 6, lane = threadIdx.x & 63, r = lane & 15, g = lane >> 4;
    int o0 = bido * 64 + w * 16, n0 = bidn * 64;
    f32x4 acc[4];
#pragma unroll
    for (int i = 0; i < 4; ++i) acc[i] = {0.f, 0.f, 0.f, 0.f};
    const u16* arow = WVB + (size_t)(o0 + r) * 256;
#pragma unroll
    for (int ks = 0; ks < 8; ++ks) {
        int k0 = ks * 32 + 8 * g;
        f16x8 a = ldh8(arow + k0);
#pragma unroll
        for (int ntl = 0; ntl < 4; ++ntl) {
            f16x8 bb = ldh8(OT + (size_t)(n0 + ntl * 16 + r) * 256 + k0);
            acc[ntl] = MFMA16(a, bb, acc[ntl]);
        }
    }
#pragma unroll
    for (int ntl = 0; ntl < 4; ++ntl) {
#pragma unroll
        for (int q = 0; q < 4; ++q) {
            int o = o0 + 4 * g + q;
            int nf = n0 + ntl * 16 + r;
            int bb = nf >> 12, n = nf & 4095;
            out[((size_t)(bb * 256 + o)) * 4096 + n] = acc[ntl][q] + bv[o];
        }
    }
}

extern "C" void kernel_launch(void* const* d_in, const int* in_sizes, int n_in,
                              void* d_out, int out_size, void* d_ws, size_t ws_size,
                              hipStream_t stream) {
    const float* x  = (const float*)d_in[0];
    const float* Wf = (const float*)d_in[1];
    const float* bf = (const float*)d_in[2];
    const float* Wg = (const float*)d_in[3];
    const float* bg = (const float*)d_in[4];
    const float* Wh = (const float*)d_in[5];
    const float* bh = (const float*)d_in[6];
    const float* Wv = (const float*)d_in[7];
    const float* bv = (const float*)d_in[8];
    float* out = (float*)d_out;
    char* ws = (char*)d_ws;

    u16* WFH = (u16*)(ws + OFF_WFH);
    u16* WFL = (u16*)(ws + OFF_WFL);
    u16* WGH = (u16*)(ws + OFF_WGH);
    u16* WGL = (u16*)(ws + OFF_WGL);
    u16* WHB = (u16*)(ws + OFF_WHB);
    u16* WVB = (u16*)(ws + OFF_WVB);
    float* ML = (float*)(ws + OFF_ML);
    u16* F   = (u16*)(ws + OFF_F);
    u16* G   = (u16*)(ws + OFF_G);
    u16* H   = (u16*)(ws + OFF_H);
    u16* XTH = (u16*)(ws + OFF_XTH);
    u16* XTL = (u16*)(ws + OFF_XTL);
    u16* OP  = (u16*)(ws + OFF_OP);   // aliases Xt (dead after convs)
    u16* OT  = (u16*)(ws + OFF_OT);   // aliases F (dead after attn)

    k_prep_w<<<256, 256, 0, stream>>>(Wf, Wg, Wh, Wv, WFH, WFL, WGH, WGL, WHB, WVB);
    k_prep_x<<<1024, 256, 0, stream>>>(x, XTH, XTL);
    k_conv_fg<<<1024, 256, 0, stream>>>(XTH, XTL, WFH, WFL, WGH, WGL, bf, bg, F, G);
    k_conv_h<<<1024, 256, 0, stream>>>(WHB, XTH, bh, H);
    k_attn<<<512, 256, 0, stream>>>(F, G, H, OP, ML);
    k_merge<<<2048, 256, 0, stream>>>(OP, ML, OT);
    k_conv_out<<<1024, 256, 0, stream>>>(WVB, OT, bv, out);
}

// Round 7
// 318.906 us; speedup vs baseline: 1.7147x; 1.0298x over previous
//
#include <hip/hip_runtime.h>
#include <hip/hip_bf16.h>

// SAGAN attention block: B=4, C=256, H=W=64 (N=4096).
// Round 7: k_attn = KVBLK=32, stage-before-compute double-buffer (one barrier
// per iter, vmcnt drain lands after full compute window), __launch_bounds__(256,2)
// with ~200 total regs -> guaranteed 2 waves/SIMD (r6: 204 arch + ~64 acc = 270
// -> 1 wave/SIMD, everything latency-exposed). Conflict-free K swizzle (9-bit
// XOR) + paired-row V layout (2-way = free). Swapped-QK 32x32, in-register P
// (cvt_pk+permlane), defer-max (T13), setprio (T5), key-split x2 + merge.

typedef short short8 __attribute__((ext_vector_type(8)));
typedef float f32x4 __attribute__((ext_vector_type(4)));
typedef float f32x16 __attribute__((ext_vector_type(16)));
typedef _Float16 f16x8 __attribute__((ext_vector_type(8)));
typedef unsigned short u16;
typedef unsigned int u32;

#define DEV static __device__ __forceinline__
#define MFMA(a, b, c)   __builtin_amdgcn_mfma_f32_16x16x32_bf16(a, b, c, 0, 0, 0)
#define MFMA16(a, b, c) __builtin_amdgcn_mfma_f32_16x16x32_f16(a, b, c, 0, 0, 0)
#define MFMA32(a, b, c) __builtin_amdgcn_mfma_f32_32x32x16_f16(a, b, c, 0, 0, 0)

DEV u16 b16(float x) {
    __hip_bfloat16 h = __float2bfloat16(x);
    return *reinterpret_cast<u16*>(&h);
}
DEV float f16f(u16 u) {
    union { unsigned int ui; float f; } c;
    c.ui = ((unsigned int)u) << 16;
    return c.f;
}
DEV u16 h16(float x) {
    union { _Float16 h; u16 u; } c;
    c.h = (_Float16)x;
    return c.u;
}
DEV short8 ld8(const u16* p) { return *reinterpret_cast<const short8*>(p); }
DEV f16x8 ldh8(const u16* p) { return *reinterpret_cast<const f16x8*>(p); }

DEV u32 cvtpk(float a, float b) {  // packed f16 (rtz): lo=a, hi=b
    u32 r;
    asm("v_cvt_pkrtz_f16_f32 %0, %1, %2" : "=v"(r) : "v"(a), "v"(b));
    return r;
}
DEV void pswap(u32& a, u32& b) {  // swap hi-32-lanes(a) <-> lo-32-lanes(b)
    asm volatile("v_permlane32_swap_b32 %0, %1" : "+v"(a), "+v"(b));
}

// async global->LDS, 16B per lane; dst is wave-uniform base, HW adds lane*16
DEV void gload16(const void* g, void* l) {
    __builtin_amdgcn_global_load_lds(
        (const __attribute__((address_space(1))) unsigned int*)g,
        (__attribute__((address_space(3))) unsigned int*)l, 16, 0, 0);
}

// ---- workspace byte offsets ----
constexpr size_t OFF_WFH = 0;         // 128K bf16 hi
constexpr size_t OFF_WFL = 131072;
constexpr size_t OFF_WGH = 262144;
constexpr size_t OFF_WGL = 393216;
constexpr size_t OFF_WHB = 524288;    // 128K bf16
constexpr size_t OFF_WVB = 655360;    // 128K fp16
constexpr size_t OFF_ML  = 786432;    // 256K f32 pairs (2 splits x 16384 x {m,l})
constexpr size_t OFF_F   = 1310720;   // 8M fp16 [m][c]   (K source)
constexpr size_t OFF_G   = OFF_F + 8388608;    // 8M fp16 [m][c]  (Q source)
constexpr size_t OFF_H   = OFF_G + 8388608;    // 8M fp16 [b][c][n] (V source)
constexpr size_t OFF_XTH = OFF_H + 8388608;    // bf16 [m][c], dead after conv_h
constexpr size_t OFF_XTL = OFF_XTH + 8388608;
constexpr size_t OFF_OP  = OFF_XTH;            // 16M fp16 (2 splits), aliases dead Xt
constexpr size_t OFF_OT  = OFF_F;              // 8M fp16, aliases dead F
// high-water mark < 52 MB

// ---------------- weight prep ----------------
__global__ __launch_bounds__(256) void k_prep_w(
    const float* __restrict__ Wf, const float* __restrict__ Wg,
    const float* __restrict__ Wh, const float* __restrict__ Wv,
    u16* WFH, u16* WFL, u16* WGH, u16* WGL, u16* WHB, u16* WVB) {
    int i = blockIdx.x * 256 + threadIdx.x;
    float fv = Wf[i];
    u16 fh = b16(fv);
    WFH[i] = fh;
    WFL[i] = b16(fv - f16f(fh));
    float gv = Wg[i];
    u16 gh = b16(gv);
    WGH[i] = gh;
    WGL[i] = b16(gv - f16f(gh));
    WHB[i] = b16(Wh[i]);
    WVB[i] = h16(Wv[i]);
}

// ---------------- x transpose + split ----------------
__global__ __launch_bounds__(256) void k_prep_x(const float* __restrict__ x, u16* XtH, u16* XtL) {
    __shared__ float lds[64][65];
    int bid = blockIdx.x;
    int b = bid >> 8, rem = bid & 255, ct = rem >> 6, nt = rem & 63;
    int tid = threadIdx.x;
    int tx = tid & 63, ty = tid >> 6;
    const float* src = x + ((size_t)(b * 256 + ct * 64)) * 4096 + nt * 64;
#pragma unroll
    for (int k = 0; k < 16; ++k) {
        int cl = ty * 16 + k;
        lds[cl][tx] = src[(size_t)cl * 4096 + tx];
    }
    __syncthreads();
    int nl = tid >> 2, cg = tid & 3;
    short8 h0, h1, l0, l1;
#pragma unroll
    for (int j = 0; j < 8; ++j) {
        float v = lds[cg * 16 + j][nl];
        u16 hb = b16(v);
        h0[j] = (short)hb;
        l0[j] = (short)b16(v - f16f(hb));
    }
#pragma unroll
    for (int j = 8; j < 16; ++j) {
        float v = lds[cg * 16 + j][nl];
        u16 hb = b16(v);
        h1[j - 8] = (short)hb;
        l1[j - 8] = (short)b16(v - f16f(hb));
    }
    size_t dst = ((size_t)(b * 4096 + nt * 64 + nl)) * 256 + ct * 64 + cg * 16;
    *reinterpret_cast<short8*>(XtH + dst) = h0;
    *reinterpret_cast<short8*>(XtH + dst + 8) = h1;
    *reinterpret_cast<short8*>(XtL + dst) = l0;
    *reinterpret_cast<short8*>(XtL + dst + 8) = l1;
}

// ---------------- conv f,g: 3-pass split-bf16 MFMA, fp16 out ----------------
__global__ __launch_bounds__(256) void k_conv_fg(
    const u16* __restrict__ XtH, const u16* __restrict__ XtL,
    const u16* __restrict__ WFH, const u16* __restrict__ WFL,
    const u16* __restrict__ WGH, const u16* __restrict__ WGL,
    const float* __restrict__ bf, const float* __restrict__ bg,
    u16* F, u16* G) {
    int bidm = blockIdx.x & 255, bido = blockIdx.x >> 8;
    int w = threadIdx.x >> 6, lane = threadIdx.x & 63, r = lane & 15, g = lane >> 4;
    int m0 = bidm * 64 + w * 16, o0 = bido * 64;
    f32x4 fa[4], ga[4];
#pragma unroll
    for (int i = 0; i < 4; ++i) { fa[i] = {0.f, 0.f, 0.f, 0.f}; ga[i] = {0.f, 0.f, 0.f, 0.f}; }
    const u16* arh = XtH + (size_t)(m0 + r) * 256;
    const u16* arl = XtL + (size_t)(m0 + r) * 256;
#pragma unroll
    for (int ks = 0; ks < 8; ++ks) {
        int k0 = ks * 32 + 8 * g;
        short8 ah = ld8(arh + k0);
        short8 al = ld8(arl + k0);
#pragma unroll
        for (int ot = 0; ot < 4; ++ot) {
            size_t wrow = (size_t)(o0 + ot * 16 + r) * 256 + k0;
            short8 wfh = ld8(WFH + wrow), wfl = ld8(WFL + wrow);
            short8 wgh = ld8(WGH + wrow), wgl = ld8(WGL + wrow);
            fa[ot] = MFMA(ah, wfh, fa[ot]);
            fa[ot] = MFMA(ah, wfl, fa[ot]);
            fa[ot] = MFMA(al, wfh, fa[ot]);
            ga[ot] = MFMA(ah, wgh, ga[ot]);
            ga[ot] = MFMA(ah, wgl, ga[ot]);
            ga[ot] = MFMA(al, wgh, ga[ot]);
        }
    }
#pragma unroll
    for (int ot = 0; ot < 4; ++ot) {
#pragma unroll
        for (int q = 0; q < 4; ++q) {
            int row = m0 + 4 * g + q;
            int col = o0 + ot * 16 + r;
            size_t idx = (size_t)row * 256 + col;
            F[idx] = h16(fa[ot][q] + bf[col]);
            G[idx] = h16(ga[ot][q] + bg[col]);
        }
    }
}

// ---------------- conv h: bf16 MFMA, fp16 out, layout [b][c][n] ----------------
__global__ __launch_bounds__(256) void k_conv_h(
    const u16* __restrict__ WHB, const u16* __restrict__ XtH,
    const float* __restrict__ bh, u16* Hb) {
    int bidn = blockIdx.x & 255, bido = blockIdx.x >> 8;
    int w = threadIdx.x >> 6, lane = threadIdx.x & 63, r = lane & 15, g = lane >> 4;
    int o0 = bido * 64 + w * 16, n0 = bidn * 64;
    f32x4 acc[4];
#pragma unroll
    for (int i = 0; i < 4; ++i) acc[i] = {0.f, 0.f, 0.f, 0.f};
    const u16* arow = WHB + (size_t)(o0 + r) * 256;
#pragma unroll
    for (int ks = 0; ks < 8; ++ks) {
        int k0 = ks * 32 + 8 * g;
        short8 a = ld8(arow + k0);
#pragma unroll
        for (int ntl = 0; ntl < 4; ++ntl) {
            short8 bb = ld8(XtH + (size_t)(n0 + ntl * 16 + r) * 256 + k0);
            acc[ntl] = MFMA(a, bb, acc[ntl]);
        }
    }
#pragma unroll
    for (int ntl = 0; ntl < 4; ++ntl) {
#pragma unroll
        for (int q = 0; q < 4; ++q) {
            int o = o0 + 4 * g + q;
            int nf = n0 + ntl * 16 + r;
            int bb = nf >> 12, n = nf & 4095;
            Hb[((size_t)(bb * 256 + o)) * 4096 + n] = h16(acc[ntl][q] + bh[o]);
        }
    }
}

// ---------------- flash attention: KVBLK=32, dbuf, 2 waves/SIMD ----------------
DEV float vmax16(const f32x16& v) {
    float a0 = fmaxf(fmaxf(v[0], v[1]), fmaxf(v[2], v[3]));
    float a1 = fmaxf(fmaxf(v[4], v[5]), fmaxf(v[6], v[7]));
    float a2 = fmaxf(fmaxf(v[8], v[9]), fmaxf(v[10], v[11]));
    float a3 = fmaxf(fmaxf(v[12], v[13]), fmaxf(v[14], v[15]));
    return fmaxf(fmaxf(a0, a1), fmaxf(a2, a3));
}
DEV float vsum16(const f32x16& v) {
    float a0 = (v[0] + v[1]) + (v[2] + v[3]);
    float a1 = (v[4] + v[5]) + (v[6] + v[7]);
    float a2 = (v[8] + v[9]) + (v[10] + v[11]);
    float a3 = (v[12] + v[13]) + (v[14] + v[15]);
    return (a0 + a1) + (a2 + a3);
}

__global__ __launch_bounds__(256, 2) void k_attn(
    const u16* __restrict__ F, const u16* __restrict__ G,
    const u16* __restrict__ Hb, u16* __restrict__ OP, float* __restrict__ ML) {
    // K tile [32 keys][256 c] fp16, 16KB, XOR swizzle ((row&7)<<4)|(((row>>3)&3)<<7).
    // V tile paired-row: byte(c,i) = (c>>1)*128 + ((i*2 + (c&1)*64) ^ (((c>>1)&7)<<4)), 16KB.
    __shared__ u16 Kd[2][8192];
    __shared__ u16 Vd[2][8192];

    int bid = blockIdx.x;            // 512 = 8 xcd * 64; ALL co-resident at 2/CU
    int xcd = bid & 7, idx = bid >> 3;
    int b = xcd >> 1, ks = xcd & 1;  // XCD carries (batch, key-half)
    int tid = threadIdx.x;
    int w = tid >> 6, lane = tid & 63;
    int qg = w >> 1, ch = w & 1;     // wave pair: same 32 queries, split channels
    int q5 = lane & 31, hi = lane >> 5;
    int j0 = idx * 64 + qg * 32;     // wave's 32 queries
    const float L2E = 1.4426950408889634f;

    // Q resident in registers as QK B-operand: lane holds column q5 of Q.
    f16x8 Qf[16];
    {
        const u16* qrow = G + (size_t)(b * 4096 + j0 + q5) * 256 + 8 * hi;
#pragma unroll
        for (int s = 0; s < 16; ++s) Qf[s] = ldh8(qrow + s * 16);
    }
    const f32x16 Z16 = {0,0,0,0,0,0,0,0,0,0,0,0,0,0,0,0};
    f32x16 O[4];                     // 32 q x 128 c (this wave's channel half)
#pragma unroll
    for (int i = 0; i < 4; ++i) O[i] = Z16;
    float mreg = -1e30f, lreg = 0.f;

    const char* Fb  = (const char*)(F + (size_t)b * 4096 * 256);
    const char* Hbb = (const char*)(Hb + (size_t)b * 256 * 4096);

    // per-lane pre-swizzled stage source offsets (dest is linear)
    int ksrc[4], vsrc[4];
#pragma unroll
    for (int t = 0; t < 4; ++t) {
        int d = (w * 4 + t) * 1024 + lane * 16;
        int row = d >> 9, col = d & 511;
        ksrc[t] = row * 512 + (col ^ (((row & 7) << 4) | (((row >> 3) & 3) << 7)));
        int r128 = d >> 7, wn = d & 127;
        int wp = wn ^ ((r128 & 7) << 4);
        vsrc[t] = ((r128 * 2 + (wp >> 6)) << 13) + (wp & 63);
    }

#define STAGE(bufn, I0)                                                         \
    do {                                                                        \
        const char* kb_ = Fb + (size_t)(I0) * 512;                              \
        const char* vb_ = Hbb + (size_t)(I0) * 2;                               \
        char* kl = (char*)Kd[bufn];                                             \
        char* vl = (char*)Vd[bufn];                                             \
        _Pragma("unroll") for (int t = 0; t < 4; ++t)                           \
            gload16(kb_ + ksrc[t], kl + (w * 4 + t) * 1024);                    \
        _Pragma("unroll") for (int t = 0; t < 4; ++t)                           \
            gload16(vb_ + vsrc[t], vl + (w * 4 + t) * 1024);                    \
    } while (0)

    int i0beg = ks * 2048;
    STAGE(0, i0beg);   // prologue
    __syncthreads();   // drains vmcnt(0): tile 0 ready

    int swk = ((q5 & 7) << 4) | (((q5 >> 3) & 3) << 7);

    for (int it = 0; it < 64; ++it) {
        int cur = it & 1;
        if (it + 1 < 64) STAGE(cur ^ 1, i0beg + (it + 1) * 32);  // fly under compute

        // ---- QK^T swapped: D[key][q] = sum_c K[key][c] * Q[q][c] ----
        const char* Kl = (const char*)Kd[cur];
        const char* Vl = (const char*)Vd[cur];
        f32x16 s = Z16;
        {
            const char* kr0 = Kl + q5 * 512;       // A row = key = lane&31
            __builtin_amdgcn_s_setprio(1);
#pragma unroll
            for (int st = 0; st < 16; ++st) {
                f16x8 ka = *reinterpret_cast<const f16x8*>(kr0 + ((st * 32 + 16 * hi) ^ swk));
                s = MFMA32(ka, Qf[st], s);
            }
            __builtin_amdgcn_s_setprio(0);
        }

        // ---- softmax: row q lane-local; reduce = in-lane tree + xor32 ----
        float v = vmax16(s);
        v = fmaxf(v, __shfl_xor(v, 32));
        float grow = v - mreg;
        if (__all(grow <= 8.0f)) {  // T13 defer-max: skip rescale
#pragma unroll
            for (int i = 0; i < 16; ++i) s[i] = exp2f((s[i] - mreg) * L2E);
            float rs = vsum16(s);
            rs += __shfl_xor(rs, 32);
            lreg += rs;
        } else {
            float mn = fmaxf(mreg, v);
            float corr = exp2f((mreg - mn) * L2E);
            mreg = mn;
#pragma unroll
            for (int i = 0; i < 16; ++i) s[i] = exp2f((s[i] - mn) * L2E);
            float rs = vsum16(s);
            rs += __shfl_xor(rs, 32);
            lreg = lreg * corr + rs;
            float cq[16];
#pragma unroll
            for (int rg = 0; rg < 16; ++rg)
                cq[rg] = __shfl(corr, (rg & 3) + 8 * (rg >> 2) + 4 * hi, 64);
#pragma unroll
            for (int ct = 0; ct < 4; ++ct)
#pragma unroll
                for (int rg = 0; rg < 16; ++rg) O[ct][rg] *= cq[rg];
        }

        // ---- P -> A-frags in-register (T12): cvt_pk + permlane32_swap ----
        union { u32 wd[8]; f16x8 fr[2]; } pu;
#pragma unroll
        for (int t = 0; t < 2; ++t) {
            int b0 = t * 8;
            u32 u0 = cvtpk(s[b0 + 0], s[b0 + 1]);
            u32 u1 = cvtpk(s[b0 + 2], s[b0 + 3]);
            u32 u2 = cvtpk(s[b0 + 4], s[b0 + 5]);
            u32 u3 = cvtpk(s[b0 + 6], s[b0 + 7]);
            pswap(u0, u2);
            pswap(u1, u3);
            pu.wd[t * 4 + 0] = u0;
            pu.wd[t * 4 + 1] = u1;
            pu.wd[t * 4 + 2] = u2;
            pu.wd[t * 4 + 3] = u3;
        }

        // ---- PV (this wave's 128-channel half): O[q][c] += P[q][i] * V[i][c] ----
        {
            __builtin_amdgcn_s_setprio(1);
#pragma unroll
            for (int ct = 0; ct < 4; ++ct) {
                int c = ch * 128 + ct * 32 + q5;
                const char* vr = Vl + (c >> 1) * 128;
                int swv = ((c >> 1) & 7) << 4;
                int cb = (c & 1) * 64;
                f16x8 vb0 = *reinterpret_cast<const f16x8*>(vr + ((16 * hi + cb) ^ swv));
                f16x8 vb1 = *reinterpret_cast<const f16x8*>(vr + ((32 + 16 * hi + cb) ^ swv));
                O[ct] = MFMA32(pu.fr[0], vb0, O[ct]);
                O[ct] = MFMA32(pu.fr[1], vb1, O[ct]);
            }
            __builtin_amdgcn_s_setprio(0);
        }

        __syncthreads();  // drains vmcnt(0) (next tile landed during compute) + all waves done
    }
#undef STAGE

    // ---- store normalized partial O (fp16) + (m,l) ----
    float linv = 1.f / lreg;
    float iq[16];
#pragma unroll
    for (int rg = 0; rg < 16; ++rg)
        iq[rg] = __shfl(linv, (rg & 3) + 8 * (rg >> 2) + 4 * hi, 64);
    u16* opb = OP + ((size_t)ks * 16384 + b * 4096 + j0) * 256;
#pragma unroll
    for (int ct = 0; ct < 4; ++ct) {
#pragma unroll
        for (int rg = 0; rg < 16; ++rg) {
            int qr = (rg & 3) + 8 * (rg >> 2) + 4 * hi;
            opb[(size_t)qr * 256 + ch * 128 + ct * 32 + q5] = h16(O[ct][rg] * iq[rg]);
        }
    }
    if (ch == 0 && hi == 0) {
        size_t mi = ((size_t)ks * 16384 + b * 4096 + j0 + q5) * 2;
        ML[mi] = mreg;
        ML[mi + 1] = lreg;
    }
}

// ---------------- merge key-splits (x2, normalized partials) -> OT fp16 [m][c] ----------------
__global__ __launch_bounds__(256) void k_merge(
    const u16* __restrict__ OP, const float* __restrict__ ML, u16* __restrict__ OT) {
    int t = blockIdx.x * 256 + threadIdx.x;  // 524288 threads
    int m = t >> 5;
    int c0 = (t & 31) * 8;
    const float L2E = 1.4426950408889634f;
    float m0 = ML[(size_t)m * 2], l0 = ML[(size_t)m * 2 + 1];
    float m1 = ML[((size_t)16384 + m) * 2], l1 = ML[((size_t)16384 + m) * 2 + 1];
    float M = fmaxf(m0, m1);
    float wl0 = exp2f((m0 - M) * L2E) * l0;
    float wl1 = exp2f((m1 - M) * L2E) * l1;
    float inv = 1.f / (wl0 + wl1);
    f16x8 v0 = ldh8(OP + (size_t)m * 256 + c0);
    f16x8 v1 = ldh8(OP + ((size_t)16384 + m) * 256 + c0);
    short8 outp;
#pragma unroll
    for (int j = 0; j < 8; ++j)
        outp[j] = (short)h16((wl0 * (float)v0[j] + wl1 * (float)v1[j]) * inv);
    *reinterpret_cast<short8*>(OT + (size_t)m * 256 + c0) = outp;
}

// ---------------- final conv: fp16 MFMA, f32 out ----------------
__global__ __launch_bounds__(256) void k_conv_out(
    const u16* __restrict__ WVB, const u16* __restrict__ OT,
    const float* __restrict__ bv, float* __restrict__ out) {
    int bidn = blockIdx.x & 255, bido = blockIdx.x >> 8;
    int w = threadIdx.x >> 6, lane = threadIdx.x & 63, r = lane & 15, g = lane >> 4;
    int o0 = bido * 64 + w * 16, n0 = bidn * 64;
    f32x4 acc[4];
#pragma unroll
    for (int i = 0; i < 4; ++i) acc[i] = {0.f, 0.f, 0.f, 0.f};
    const u16* arow = WVB + (size_t)(o0 + r) * 256;
#pragma unroll
    for (int ks = 0; ks < 8; ++ks) {
        int k0 = ks * 32 + 8 * g;
        f16x8 a = ldh8(arow + k0);
#pragma unroll
        for (int ntl = 0; ntl < 4; ++ntl) {
            f16x8 bb = ldh8(OT + (size_t)(n0 + ntl * 16 + r) * 256 + k0);
            acc[ntl] = MFMA16(a, bb, acc[ntl]);
        }
    }
#pragma unroll
    for (int ntl = 0; ntl < 4; ++ntl) {
#pragma unroll
        for (int q = 0; q < 4; ++q) {
            int o = o0 + 4 * g + q;
            int nf = n0 + ntl * 16 + r;
            int bb = nf >> 12, n = nf & 4095;
            out[((size_t)(bb * 256 + o)) * 4096 + n] = acc[ntl][q] + bv[o];
        }
    }
}

extern "C" void kernel_launch(void* const* d_in, const int* in_sizes, int n_in,
                              void* d_out, int out_size, void* d_ws, size_t ws_size,
                              hipStream_t stream) {
    const float* x  = (const float*)d_in[0];
    const float* Wf = (const float*)d_in[1];
    const float* bf = (const float*)d_in[2];
    const float* Wg = (const float*)d_in[3];
    const float* bg = (const float*)d_in[4];
    const float* Wh = (const float*)d_in[5];
    const float* bh = (const float*)d_in[6];
    const float* Wv = (const float*)d_in[7];
    const float* bv = (const float*)d_in[8];
    float* out = (float*)d_out;
    char* ws = (char*)d_ws;

    u16* WFH = (u16*)(ws + OFF_WFH);
    u16* WFL = (u16*)(ws + OFF_WFL);
    u16* WGH = (u16*)(ws + OFF_WGH);
    u16* WGL = (u16*)(ws + OFF_WGL);
    u16* WHB = (u16*)(ws + OFF_WHB);
    u16* WVB = (u16*)(ws + OFF_WVB);
    float* ML = (float*)(ws + OFF_ML);
    u16* F   = (u16*)(ws + OFF_F);
    u16* G   = (u16*)(ws + OFF_G);
    u16* H   = (u16*)(ws + OFF_H);
    u16* XTH = (u16*)(ws + OFF_XTH);
    u16* XTL = (u16*)(ws + OFF_XTL);
    u16* OP  = (u16*)(ws + OFF_OP);   // aliases Xt (dead after convs)
    u16* OT  = (u16*)(ws + OFF_OT);   // aliases F (dead after attn)

    k_prep_w<<<256, 256, 0, stream>>>(Wf, Wg, Wh, Wv, WFH, WFL, WGH, WGL, WHB, WVB);
    k_prep_x<<<1024, 256, 0, stream>>>(x, XTH, XTL);
    k_conv_fg<<<1024, 256, 0, stream>>>(XTH, XTL, WFH, WFL, WGH, WGL, bf, bg, F, G);
    k_conv_h<<<1024, 256, 0, stream>>>(WHB, XTH, bh, H);
    k_attn<<<512, 256, 0, stream>>>(F, G, H, OP, ML);
    k_merge<<<2048, 256, 0, stream>>>(OP, ML, OT);
    k_conv_out<<<1024, 256, 0, stream>>>(WVB, OT, bv, out);
}

// Round 8
// 288.171 us; speedup vs baseline: 1.8976x; 1.1067x over previous
//
#include <hip/hip_runtime.h>
#include <hip/hip_bf16.h>

// SAGAN attention block: B=4, C=256, H=W=64 (N=4096).
// Round 8: revert attn to round-3's 16x16 structure (VGPR ~140, no spill,
// 2 blocks/CU) + verified deltas: KVBLK=32 double-buffer with stage-before-
// compute (1 barrier/iter), wave-private padded P (no cross-wave P barriers),
// defer-max (T13), paired-row V layout (2-way = free). Key-split x2 + merge.

typedef short short8 __attribute__((ext_vector_type(8)));
typedef float f32x4 __attribute__((ext_vector_type(4)));
typedef _Float16 f16x8 __attribute__((ext_vector_type(8)));
typedef unsigned short u16;
typedef unsigned int u32;

#define DEV static __device__ __forceinline__
#define MFMA(a, b, c)   __builtin_amdgcn_mfma_f32_16x16x32_bf16(a, b, c, 0, 0, 0)
#define MFMA16(a, b, c) __builtin_amdgcn_mfma_f32_16x16x32_f16(a, b, c, 0, 0, 0)

DEV u16 b16(float x) {
    __hip_bfloat16 h = __float2bfloat16(x);
    return *reinterpret_cast<u16*>(&h);
}
DEV float f16f(u16 u) {
    union { unsigned int ui; float f; } c;
    c.ui = ((unsigned int)u) << 16;
    return c.f;
}
DEV u16 h16(float x) {
    union { _Float16 h; u16 u; } c;
    c.h = (_Float16)x;
    return c.u;
}
DEV short8 ld8(const u16* p) { return *reinterpret_cast<const short8*>(p); }
DEV f16x8 ldh8(const u16* p) { return *reinterpret_cast<const f16x8*>(p); }

// async global->LDS, 16B per lane; dst is wave-uniform base, HW adds lane*16
DEV void gload16(const void* g, void* l) {
    __builtin_amdgcn_global_load_lds(
        (const __attribute__((address_space(1))) unsigned int*)g,
        (__attribute__((address_space(3))) unsigned int*)l, 16, 0, 0);
}

// ---- workspace byte offsets ----
constexpr size_t OFF_WFH = 0;         // 128K bf16 hi
constexpr size_t OFF_WFL = 131072;
constexpr size_t OFF_WGH = 262144;
constexpr size_t OFF_WGL = 393216;
constexpr size_t OFF_WHB = 524288;    // 128K bf16
constexpr size_t OFF_WVB = 655360;    // 128K fp16
constexpr size_t OFF_ML  = 786432;    // 256K f32 pairs (2 splits x 16384 x {m,l})
constexpr size_t OFF_F   = 1310720;   // 8M fp16 [m][c]   (K source)
constexpr size_t OFF_G   = OFF_F + 8388608;    // 8M fp16 [m][c]  (Q source)
constexpr size_t OFF_H   = OFF_G + 8388608;    // 8M fp16 [b][c][n] (V source)
constexpr size_t OFF_XTH = OFF_H + 8388608;    // bf16 [m][c], dead after conv_h
constexpr size_t OFF_XTL = OFF_XTH + 8388608;
constexpr size_t OFF_OP  = OFF_XTH;            // 16M fp16 (2 splits), aliases dead Xt
constexpr size_t OFF_OT  = OFF_F;              // 8M fp16, aliases dead F
// high-water mark < 52 MB

// ---------------- weight prep ----------------
__global__ __launch_bounds__(256) void k_prep_w(
    const float* __restrict__ Wf, const float* __restrict__ Wg,
    const float* __restrict__ Wh, const float* __restrict__ Wv,
    u16* WFH, u16* WFL, u16* WGH, u16* WGL, u16* WHB, u16* WVB) {
    int i = blockIdx.x * 256 + threadIdx.x;
    float fv = Wf[i];
    u16 fh = b16(fv);
    WFH[i] = fh;
    WFL[i] = b16(fv - f16f(fh));
    float gv = Wg[i];
    u16 gh = b16(gv);
    WGH[i] = gh;
    WGL[i] = b16(gv - f16f(gh));
    WHB[i] = b16(Wh[i]);
    WVB[i] = h16(Wv[i]);
}

// ---------------- x transpose + split ----------------
__global__ __launch_bounds__(256) void k_prep_x(const float* __restrict__ x, u16* XtH, u16* XtL) {
    __shared__ float lds[64][65];
    int bid = blockIdx.x;
    int b = bid >> 8, rem = bid & 255, ct = rem >> 6, nt = rem & 63;
    int tid = threadIdx.x;
    int tx = tid & 63, ty = tid >> 6;
    const float* src = x + ((size_t)(b * 256 + ct * 64)) * 4096 + nt * 64;
#pragma unroll
    for (int k = 0; k < 16; ++k) {
        int cl = ty * 16 + k;
        lds[cl][tx] = src[(size_t)cl * 4096 + tx];
    }
    __syncthreads();
    int nl = tid >> 2, cg = tid & 3;
    short8 h0, h1, l0, l1;
#pragma unroll
    for (int j = 0; j < 8; ++j) {
        float v = lds[cg * 16 + j][nl];
        u16 hb = b16(v);
        h0[j] = (short)hb;
        l0[j] = (short)b16(v - f16f(hb));
    }
#pragma unroll
    for (int j = 8; j < 16; ++j) {
        float v = lds[cg * 16 + j][nl];
        u16 hb = b16(v);
        h1[j - 8] = (short)hb;
        l1[j - 8] = (short)b16(v - f16f(hb));
    }
    size_t dst = ((size_t)(b * 4096 + nt * 64 + nl)) * 256 + ct * 64 + cg * 16;
    *reinterpret_cast<short8*>(XtH + dst) = h0;
    *reinterpret_cast<short8*>(XtH + dst + 8) = h1;
    *reinterpret_cast<short8*>(XtL + dst) = l0;
    *reinterpret_cast<short8*>(XtL + dst + 8) = l1;
}

// ---------------- conv f,g: 3-pass split-bf16 MFMA, fp16 out ----------------
__global__ __launch_bounds__(256) void k_conv_fg(
    const u16* __restrict__ XtH, const u16* __restrict__ XtL,
    const u16* __restrict__ WFH, const u16* __restrict__ WFL,
    const u16* __restrict__ WGH, const u16* __restrict__ WGL,
    const float* __restrict__ bf, const float* __restrict__ bg,
    u16* F, u16* G) {
    int bidm = blockIdx.x & 255, bido = blockIdx.x >> 8;
    int w = threadIdx.x >> 6, lane = threadIdx.x & 63, r = lane & 15, g = lane >> 4;
    int m0 = bidm * 64 + w * 16, o0 = bido * 64;
    f32x4 fa[4], ga[4];
#pragma unroll
    for (int i = 0; i < 4; ++i) { fa[i] = {0.f, 0.f, 0.f, 0.f}; ga[i] = {0.f, 0.f, 0.f, 0.f}; }
    const u16* arh = XtH + (size_t)(m0 + r) * 256;
    const u16* arl = XtL + (size_t)(m0 + r) * 256;
#pragma unroll
    for (int ks = 0; ks < 8; ++ks) {
        int k0 = ks * 32 + 8 * g;
        short8 ah = ld8(arh + k0);
        short8 al = ld8(arl + k0);
#pragma unroll
        for (int ot = 0; ot < 4; ++ot) {
            size_t wrow = (size_t)(o0 + ot * 16 + r) * 256 + k0;
            short8 wfh = ld8(WFH + wrow), wfl = ld8(WFL + wrow);
            short8 wgh = ld8(WGH + wrow), wgl = ld8(WGL + wrow);
            fa[ot] = MFMA(ah, wfh, fa[ot]);
            fa[ot] = MFMA(ah, wfl, fa[ot]);
            fa[ot] = MFMA(al, wfh, fa[ot]);
            ga[ot] = MFMA(ah, wgh, ga[ot]);
            ga[ot] = MFMA(ah, wgl, ga[ot]);
            ga[ot] = MFMA(al, wgh, ga[ot]);
        }
    }
#pragma unroll
    for (int ot = 0; ot < 4; ++ot) {
#pragma unroll
        for (int q = 0; q < 4; ++q) {
            int row = m0 + 4 * g + q;
            int col = o0 + ot * 16 + r;
            size_t idx = (size_t)row * 256 + col;
            F[idx] = h16(fa[ot][q] + bf[col]);
            G[idx] = h16(ga[ot][q] + bg[col]);
        }
    }
}

// ---------------- conv h: bf16 MFMA, fp16 out, layout [b][c][n] ----------------
__global__ __launch_bounds__(256) void k_conv_h(
    const u16* __restrict__ WHB, const u16* __restrict__ XtH,
    const float* __restrict__ bh, u16* Hb) {
    int bidn = blockIdx.x & 255, bido = blockIdx.x >> 8;
    int w = threadIdx.x >> 6, lane = threadIdx.x & 63, r = lane & 15, g = lane >> 4;
    int o0 = bido * 64 + w * 16, n0 = bidn * 64;
    f32x4 acc[4];
#pragma unroll
    for (int i = 0; i < 4; ++i) acc[i] = {0.f, 0.f, 0.f, 0.f};
    const u16* arow = WHB + (size_t)(o0 + r) * 256;
#pragma unroll
    for (int ks = 0; ks < 8; ++ks) {
        int k0 = ks * 32 + 8 * g;
        short8 a = ld8(arow + k0);
#pragma unroll
        for (int ntl = 0; ntl < 4; ++ntl) {
            short8 bb = ld8(XtH + (size_t)(n0 + ntl * 16 + r) * 256 + k0);
            acc[ntl] = MFMA(a, bb, acc[ntl]);
        }
    }
#pragma unroll
    for (int ntl = 0; ntl < 4; ++ntl) {
#pragma unroll
        for (int q = 0; q < 4; ++q) {
            int o = o0 + 4 * g + q;
            int nf = n0 + ntl * 16 + r;
            int bb = nf >> 12, n = nf & 4095;
            Hb[((size_t)(bb * 256 + o)) * 4096 + n] = h16(acc[ntl][q] + bh[o]);
        }
    }
}

// ---------------- flash attention: 16x16, KVBLK=32 dbuf, private P, defer-max ----------------
DEV float rmax16(float v) {
    v = fmaxf(v, __shfl_xor(v, 1));
    v = fmaxf(v, __shfl_xor(v, 2));
    v = fmaxf(v, __shfl_xor(v, 4));
    v = fmaxf(v, __shfl_xor(v, 8));
    return v;
}
DEV float rsum16(float v) {
    v += __shfl_xor(v, 1);
    v += __shfl_xor(v, 2);
    v += __shfl_xor(v, 4);
    v += __shfl_xor(v, 8);
    return v;
}

__global__ __launch_bounds__(256, 2) void k_attn(
    const u16* __restrict__ F, const u16* __restrict__ G,
    const u16* __restrict__ Hb, u16* __restrict__ OP, float* __restrict__ ML) {
    // K tile [32 keys][256 c] fp16, 16KB each, swizzle byte ^= (row&7)<<4.
    // V tile paired-row: byte(c,i) = (c>>1)*128 + ((i*2 + (c&1)*64) ^ (((c>>1)&7)<<4)).
    __shared__ u16 Kd[2][8192];
    __shared__ u16 Vd[2][8192];
    __shared__ u16 Pd[4][1152];   // wave-private P[16][72]

    int bid = blockIdx.x;            // 512 = 8 xcd * 64; 2 blocks/CU
    int xcd = bid & 7, idx = bid >> 3;
    int b = xcd >> 1, ks = xcd & 1;  // XCD carries (batch, key-half)
    int tid = threadIdx.x;
    int w = tid >> 6, lane = tid & 63, r = lane & 15, g = lane >> 4;
    int j0 = idx * 64 + w * 16;      // wave's 16 queries
    const float L2E = 1.4426950408889634f;

    // Q resident in registers: A-frag rows j=r
    f16x8 Qf[8];
    {
        const u16* q = G + (size_t)(b * 4096 + j0 + r) * 256;
#pragma unroll
        for (int k = 0; k < 8; ++k) Qf[k] = ldh8(q + k * 32 + 8 * g);
    }
    f32x4 O[16];
#pragma unroll
    for (int i = 0; i < 16; ++i) O[i] = {0.f, 0.f, 0.f, 0.f};
    float m[4], l[4];
#pragma unroll
    for (int q = 0; q < 4; ++q) { m[q] = -1e30f; l[q] = 0.f; }

    const char* Fb  = (const char*)(F + (size_t)b * 4096 * 256);
    const char* Hbb = (const char*)(Hb + (size_t)b * 256 * 4096);
    u16* Pw = Pd[w];

    // per-lane pre-swizzled stage source offsets (dest is linear)
    int ksrc[4], vsrc[4];
#pragma unroll
    for (int t = 0; t < 4; ++t) {
        int d = (w * 4 + t) * 1024 + lane * 16;
        int row = d >> 9, col = d & 511;
        ksrc[t] = row * 512 + (col ^ ((row & 7) << 4));
        int r128 = d >> 7, wn = d & 127;
        int wp = wn ^ ((r128 & 7) << 4);
        vsrc[t] = ((r128 * 2 + (wp >> 6)) << 13) + (wp & 63);
    }

#define STAGE(bufn, I0)                                                         \
    do {                                                                        \
        const char* kb_ = Fb + (size_t)(I0) * 512;                              \
        const char* vb_ = Hbb + (size_t)(I0) * 2;                               \
        char* kl = (char*)Kd[bufn];                                             \
        char* vl = (char*)Vd[bufn];                                             \
        _Pragma("unroll") for (int t = 0; t < 4; ++t)                           \
            gload16(kb_ + ksrc[t], kl + (w * 4 + t) * 1024);                    \
        _Pragma("unroll") for (int t = 0; t < 4; ++t)                           \
            gload16(vb_ + vsrc[t], vl + (w * 4 + t) * 1024);                    \
    } while (0)

    int i0beg = ks * 2048;
    STAGE(0, i0beg);   // prologue
    __syncthreads();   // drains vmcnt(0): tile 0 ready

    for (int it = 0; it < 64; ++it) {
        int cur = it & 1;
        if (it + 1 < 64) STAGE(cur ^ 1, i0beg + (it + 1) * 32);  // fly under compute

        const char* Kl = (const char*)Kd[cur];
        const char* Vl = (const char*)Vd[cur];

        // ---- QK^T: S'[j][i], B-frags from swizzled K tile ----
        f32x4 s[2];
        s[0] = {0.f, 0.f, 0.f, 0.f};
        s[1] = {0.f, 0.f, 0.f, 0.f};
        __builtin_amdgcn_s_setprio(1);
#pragma unroll
        for (int it2 = 0; it2 < 2; ++it2) {
            int row = it2 * 16 + r;
            const char* kr = Kl + row * 512;
            int sw = (row & 7) << 4;
#pragma unroll
            for (int k = 0; k < 8; ++k) {
                f16x8 kb = *reinterpret_cast<const f16x8*>(kr + ((k * 64 + 16 * g) ^ sw));
                s[it2] = MFMA16(Qf[k], kb, s[it2]);
            }
        }
        __builtin_amdgcn_s_setprio(0);

        // ---- online softmax (defer-max, THR=8); row j=4g+q across 16 lanes ----
        float nm[4], grow = -1e30f;
#pragma unroll
        for (int q = 0; q < 4; ++q) {
            float v = fmaxf(s[0][q], s[1][q]);
            v = rmax16(v);
            nm[q] = v;
            grow = fmaxf(grow, v - m[q]);
        }
        if (__all(grow <= 8.0f)) {
#pragma unroll
            for (int q = 0; q < 4; ++q) {
                float p0 = exp2f((s[0][q] - m[q]) * L2E);
                float p1 = exp2f((s[1][q] - m[q]) * L2E);
                s[0][q] = p0;
                s[1][q] = p1;
                l[q] += rsum16(p0 + p1);
            }
        } else {
            float corr[4];
#pragma unroll
            for (int q = 0; q < 4; ++q) {
                float mn = fmaxf(m[q], nm[q]);
                corr[q] = exp2f((m[q] - mn) * L2E);
                float p0 = exp2f((s[0][q] - mn) * L2E);
                float p1 = exp2f((s[1][q] - mn) * L2E);
                s[0][q] = p0;
                s[1][q] = p1;
                l[q] = l[q] * corr[q] + rsum16(p0 + p1);
                m[q] = mn;
            }
#pragma unroll
            for (int ct = 0; ct < 16; ++ct) {
                O[ct][0] *= corr[0];
                O[ct][1] *= corr[1];
                O[ct][2] *= corr[2];
                O[ct][3] *= corr[3];
            }
        }

        // ---- P -> wave-private LDS (D-layout), re-read as A-frag ----
#pragma unroll
        for (int it2 = 0; it2 < 2; ++it2) {
#pragma unroll
            for (int q = 0; q < 4; ++q) Pw[(4 * g + q) * 72 + it2 * 16 + r] = h16(s[it2][q]);
        }
        __asm__ volatile("s_waitcnt lgkmcnt(0)" ::: "memory");
        f16x8 pa = *reinterpret_cast<const f16x8*>((const char*)Pw + r * 144 + 16 * g);

        // ---- PV: O[j][c] += P[j][i] * V[i][c], B-frags from paired-row V ----
        __builtin_amdgcn_s_setprio(1);
#pragma unroll
        for (int ct = 0; ct < 16; ++ct) {
            int c = ct * 16 + r;
            const char* vr = Vl + (c >> 1) * 128;
            int swv = ((c >> 1) & 7) << 4;
            int cb = (c & 1) * 64;
            f16x8 vb = *reinterpret_cast<const f16x8*>(vr + ((16 * g + cb) ^ swv));
            O[ct] = MFMA16(pa, vb, O[ct]);
        }
        __builtin_amdgcn_s_setprio(0);

        __syncthreads();  // drains vmcnt (next tile landed during compute); buffer reuse safe
    }
#undef STAGE

    // ---- store normalized partial O (fp16) + (m,l) ----
    float inv[4];
#pragma unroll
    for (int q = 0; q < 4; ++q) inv[q] = 1.f / l[q];
#pragma unroll
    for (int ct = 0; ct < 16; ++ct) {
#pragma unroll
        for (int q = 0; q < 4; ++q) {
            OP[((size_t)ks * 16384 + b * 4096 + j0 + 4 * g + q) * 256 + ct * 16 + r] =
                h16(O[ct][q] * inv[q]);
        }
    }
    if (r == 0) {
#pragma unroll
        for (int q = 0; q < 4; ++q) {
            size_t mi = ((size_t)ks * 16384 + b * 4096 + j0 + 4 * g + q) * 2;
            ML[mi] = m[q];
            ML[mi + 1] = l[q];
        }
    }
}

// ---------------- merge key-splits (x2, normalized partials) -> OT fp16 [m][c] ----------------
__global__ __launch_bounds__(256) void k_merge(
    const u16* __restrict__ OP, const float* __restrict__ ML, u16* __restrict__ OT) {
    int t = blockIdx.x * 256 + threadIdx.x;  // 524288 threads
    int m = t >> 5;
    int c0 = (t & 31) * 8;
    const float L2E = 1.4426950408889634f;
    float m0 = ML[(size_t)m * 2], l0 = ML[(size_t)m * 2 + 1];
    float m1 = ML[((size_t)16384 + m) * 2], l1 = ML[((size_t)16384 + m) * 2 + 1];
    float M = fmaxf(m0, m1);
    float wl0 = exp2f((m0 - M) * L2E) * l0;
    float wl1 = exp2f((m1 - M) * L2E) * l1;
    float inv = 1.f / (wl0 + wl1);
    f16x8 v0 = ldh8(OP + (size_t)m * 256 + c0);
    f16x8 v1 = ldh8(OP + ((size_t)16384 + m) * 256 + c0);
    short8 outp;
#pragma unroll
    for (int j = 0; j < 8; ++j)
        outp[j] = (short)h16((wl0 * (float)v0[j] + wl1 * (float)v1[j]) * inv);
    *reinterpret_cast<short8*>(OT + (size_t)m * 256 + c0) = outp;
}

// ---------------- final conv: fp16 MFMA, f32 out ----------------
__global__ __launch_bounds__(256) void k_conv_out(
    const u16* __restrict__ WVB, const u16* __restrict__ OT,
    const float* __restrict__ bv, float* __restrict__ out) {
    int bidn = blockIdx.x & 255, bido = blockIdx.x >> 8;
    int w = threadIdx.x >> 6, lane = threadIdx.x & 63, r = lane & 15, g = lane >> 4;
    int o0 = bido * 64 + w * 16, n0 = bidn * 64;
    f32x4 acc[4];
#pragma unroll
    for (int i = 0; i < 4; ++i) acc[i] = {0.f, 0.f, 0.f, 0.f};
    const u16* arow = WVB + (size_t)(o0 + r) * 256;
#pragma unroll
    for (int ks = 0; ks < 8; ++ks) {
        int k0 = ks * 32 + 8 * g;
        f16x8 a = ldh8(arow + k0);
#pragma unroll
        for (int ntl = 0; ntl < 4; ++ntl) {
            f16x8 bb = ldh8(OT + (size_t)(n0 + ntl * 16 + r) * 256 + k0);
            acc[ntl] = MFMA16(a, bb, acc[ntl]);
        }
    }
#pragma unroll
    for (int ntl = 0; ntl < 4; ++ntl) {
#pragma unroll
        for (int q = 0; q < 4; ++q) {
            int o = o0 + 4 * g + q;
            int nf = n0 + ntl * 16 + r;
            int bb = nf >> 12, n = nf & 4095;
            out[((size_t)(bb * 256 + o)) * 4096 + n] = acc[ntl][q] + bv[o];
        }
    }
}

extern "C" void kernel_launch(void* const* d_in, const int* in_sizes, int n_in,
                              void* d_out, int out_size, void* d_ws, size_t ws_size,
                              hipStream_t stream) {
    const float* x  = (const float*)d_in[0];
    const float* Wf = (const float*)d_in[1];
    const float* bf = (const float*)d_in[2];
    const float* Wg = (const float*)d_in[3];
    const float* bg = (const float*)d_in[4];
    const float* Wh = (const float*)d_in[5];
    const float* bh = (const float*)d_in[6];
    const float* Wv = (const float*)d_in[7];
    const float* bv = (const float*)d_in[8];
    float* out = (float*)d_out;
    char* ws = (char*)d_ws;

    u16* WFH = (u16*)(ws + OFF_WFH);
    u16* WFL = (u16*)(ws + OFF_WFL);
    u16* WGH = (u16*)(ws + OFF_WGH);
    u16* WGL = (u16*)(ws + OFF_WGL);
    u16* WHB = (u16*)(ws + OFF_WHB);
    u16* WVB = (u16*)(ws + OFF_WVB);
    float* ML = (float*)(ws + OFF_ML);
    u16* F   = (u16*)(ws + OFF_F);
    u16* G   = (u16*)(ws + OFF_G);
    u16* H   = (u16*)(ws + OFF_H);
    u16* XTH = (u16*)(ws + OFF_XTH);
    u16* XTL = (u16*)(ws + OFF_XTL);
    u16* OP  = (u16*)(ws + OFF_OP);   // aliases Xt (dead after convs)
    u16* OT  = (u16*)(ws + OFF_OT);   // aliases F (dead after attn)

    k_prep_w<<<256, 256, 0, stream>>>(Wf, Wg, Wh, Wv, WFH, WFL, WGH, WGL, WHB, WVB);
    k_prep_x<<<1024, 256, 0, stream>>>(x, XTH, XTL);
    k_conv_fg<<<1024, 256, 0, stream>>>(XTH, XTL, WFH, WFL, WGH, WGL, bf, bg, F, G);
    k_conv_h<<<1024, 256, 0, stream>>>(WHB, XTH, bh, H);
    k_attn<<<512, 256, 0, stream>>>(F, G, H, OP, ML);
    k_merge<<<2048, 256, 0, stream>>>(OP, ML, OT);
    k_conv_out<<<1024, 256, 0, stream>>>(WVB, OT, bv, out);
}

// Round 10
// 252.951 us; speedup vs baseline: 2.1618x; 1.1392x over previous
//
#include <hip/hip_runtime.h>
#include <hip/hip_bf16.h>

// SAGAN attention block: B=4, C=256, H=W=64 (N=4096).
// Round 10: r9's intent with proven primitives only. conv_h stores V with keys
// permuted within each 32-block so the PV B-fragment is LANE-LOCAL after
// swapped QK (mfma(K,Q)): P->B-frag = 4 cvtpk, no cross-lane transpose at all
// (r9's permlane16 path was miscompiled/unvalidated -> absmax 1.9e4).
// Softmax: lane-scalar + 2+2 shfl_xor(16/32). No P LDS round-trip.
// Base structure = r8 (16x16, KVBLK=32 dbuf, (256,2), key-split x2 + merge).

typedef short short8 __attribute__((ext_vector_type(8)));
typedef short short4v __attribute__((ext_vector_type(4)));
typedef float f32x4 __attribute__((ext_vector_type(4)));
typedef _Float16 f16x8 __attribute__((ext_vector_type(8)));
typedef unsigned short u16;
typedef unsigned int u32;

#define DEV static __device__ __forceinline__
#define MFMA(a, b, c)   __builtin_amdgcn_mfma_f32_16x16x32_bf16(a, b, c, 0, 0, 0)
#define MFMA16(a, b, c) __builtin_amdgcn_mfma_f32_16x16x32_f16(a, b, c, 0, 0, 0)

DEV u16 b16(float x) {
    __hip_bfloat16 h = __float2bfloat16(x);
    return *reinterpret_cast<u16*>(&h);
}
DEV float f16f(u16 u) {
    union { unsigned int ui; float f; } c;
    c.ui = ((unsigned int)u) << 16;
    return c.f;
}
DEV u16 h16(float x) {
    union { _Float16 h; u16 u; } c;
    c.h = (_Float16)x;
    return c.u;
}
DEV short8 ld8(const u16* p) { return *reinterpret_cast<const short8*>(p); }
DEV f16x8 ldh8(const u16* p) { return *reinterpret_cast<const f16x8*>(p); }

DEV u32 cvtpk(float a, float b) {  // packed f16 (rtz): lo=a, hi=b
    u32 r;
    asm("v_cvt_pkrtz_f16_f32 %0, %1, %2" : "=v"(r) : "v"(a), "v"(b));
    return r;
}

// async global->LDS, 16B per lane; dst is wave-uniform base, HW adds lane*16
DEV void gload16(const void* g, void* l) {
    __builtin_amdgcn_global_load_lds(
        (const __attribute__((address_space(1))) unsigned int*)g,
        (__attribute__((address_space(3))) unsigned int*)l, 16, 0, 0);
}

// ---- workspace byte offsets ----
constexpr size_t OFF_WFH = 0;         // 128K bf16 hi
constexpr size_t OFF_WFL = 131072;
constexpr size_t OFF_WGH = 262144;
constexpr size_t OFF_WGL = 393216;
constexpr size_t OFF_WHB = 524288;    // 128K bf16
constexpr size_t OFF_WVB = 655360;    // 128K fp16
constexpr size_t OFF_ML  = 786432;    // 256K f32 pairs (2 splits x 16384 x {m,l})
constexpr size_t OFF_F   = 1310720;   // 8M fp16 [m][c]   (K source)
constexpr size_t OFF_G   = OFF_F + 8388608;    // 8M fp16 [m][c]  (Q source)
constexpr size_t OFF_H   = OFF_G + 8388608;    // 8M fp16 [b][c][n] (V source, key-permuted per 32-block)
constexpr size_t OFF_XTH = OFF_H + 8388608;    // bf16 [m][c], dead after conv_h
constexpr size_t OFF_XTL = OFF_XTH + 8388608;
constexpr size_t OFF_OP  = OFF_XTH;            // 16M fp16 (2 splits), aliases dead Xt
constexpr size_t OFF_OT  = OFF_F;              // 8M fp16, aliases dead F
// high-water mark < 52 MB

// ---------------- weight prep ----------------
__global__ __launch_bounds__(256) void k_prep_w(
    const float* __restrict__ Wf, const float* __restrict__ Wg,
    const float* __restrict__ Wh, const float* __restrict__ Wv,
    u16* WFH, u16* WFL, u16* WGH, u16* WGL, u16* WHB, u16* WVB) {
    int i = blockIdx.x * 256 + threadIdx.x;
    float fv = Wf[i];
    u16 fh = b16(fv);
    WFH[i] = fh;
    WFL[i] = b16(fv - f16f(fh));
    float gv = Wg[i];
    u16 gh = b16(gv);
    WGH[i] = gh;
    WGL[i] = b16(gv - f16f(gh));
    WHB[i] = b16(Wh[i]);
    WVB[i] = h16(Wv[i]);
}

// ---------------- x transpose + split ----------------
__global__ __launch_bounds__(256) void k_prep_x(const float* __restrict__ x, u16* XtH, u16* XtL) {
    __shared__ float lds[64][65];
    int bid = blockIdx.x;
    int b = bid >> 8, rem = bid & 255, ct = rem >> 6, nt = rem & 63;
    int tid = threadIdx.x;
    int tx = tid & 63, ty = tid >> 6;
    const float* src = x + ((size_t)(b * 256 + ct * 64)) * 4096 + nt * 64;
#pragma unroll
    for (int k = 0; k < 16; ++k) {
        int cl = ty * 16 + k;
        lds[cl][tx] = src[(size_t)cl * 4096 + tx];
    }
    __syncthreads();
    int nl = tid >> 2, cg = tid & 3;
    short8 h0, h1, l0, l1;
#pragma unroll
    for (int j = 0; j < 8; ++j) {
        float v = lds[cg * 16 + j][nl];
        u16 hb = b16(v);
        h0[j] = (short)hb;
        l0[j] = (short)b16(v - f16f(hb));
    }
#pragma unroll
    for (int j = 8; j < 16; ++j) {
        float v = lds[cg * 16 + j][nl];
        u16 hb = b16(v);
        h1[j - 8] = (short)hb;
        l1[j - 8] = (short)b16(v - f16f(hb));
    }
    size_t dst = ((size_t)(b * 4096 + nt * 64 + nl)) * 256 + ct * 64 + cg * 16;
    *reinterpret_cast<short8*>(XtH + dst) = h0;
    *reinterpret_cast<short8*>(XtH + dst + 8) = h1;
    *reinterpret_cast<short8*>(XtL + dst) = l0;
    *reinterpret_cast<short8*>(XtL + dst + 8) = l1;
}

// ---------------- conv f,g: 3-pass split-bf16 MFMA, fp16 out ----------------
__global__ __launch_bounds__(256) void k_conv_fg(
    const u16* __restrict__ XtH, const u16* __restrict__ XtL,
    const u16* __restrict__ WFH, const u16* __restrict__ WFL,
    const u16* __restrict__ WGH, const u16* __restrict__ WGL,
    const float* __restrict__ bf, const float* __restrict__ bg,
    u16* F, u16* G) {
    int bidm = blockIdx.x & 255, bido = blockIdx.x >> 8;
    int w = threadIdx.x >> 6, lane = threadIdx.x & 63, r = lane & 15, g = lane >> 4;
    int m0 = bidm * 64 + w * 16, o0 = bido * 64;
    f32x4 fa[4], ga[4];
#pragma unroll
    for (int i = 0; i < 4; ++i) { fa[i] = {0.f, 0.f, 0.f, 0.f}; ga[i] = {0.f, 0.f, 0.f, 0.f}; }
    const u16* arh = XtH + (size_t)(m0 + r) * 256;
    const u16* arl = XtL + (size_t)(m0 + r) * 256;
#pragma unroll
    for (int ks = 0; ks < 8; ++ks) {
        int k0 = ks * 32 + 8 * g;
        short8 ah = ld8(arh + k0);
        short8 al = ld8(arl + k0);
#pragma unroll
        for (int ot = 0; ot < 4; ++ot) {
            size_t wrow = (size_t)(o0 + ot * 16 + r) * 256 + k0;
            short8 wfh = ld8(WFH + wrow), wfl = ld8(WFL + wrow);
            short8 wgh = ld8(WGH + wrow), wgl = ld8(WGL + wrow);
            fa[ot] = MFMA(ah, wfh, fa[ot]);
            fa[ot] = MFMA(ah, wfl, fa[ot]);
            fa[ot] = MFMA(al, wfh, fa[ot]);
            ga[ot] = MFMA(ah, wgh, ga[ot]);
            ga[ot] = MFMA(ah, wgl, ga[ot]);
            ga[ot] = MFMA(al, wgh, ga[ot]);
        }
    }
#pragma unroll
    for (int ot = 0; ot < 4; ++ot) {
#pragma unroll
        for (int q = 0; q < 4; ++q) {
            int row = m0 + 4 * g + q;
            int col = o0 + ot * 16 + r;
            size_t idx = (size_t)row * 256 + col;
            F[idx] = h16(fa[ot][q] + bf[col]);
            G[idx] = h16(ga[ot][q] + bg[col]);
        }
    }
}

// ---------------- conv h: bf16 MFMA, fp16 out, layout [b][c][n], keys permuted per 32-block ----------------
__global__ __launch_bounds__(256) void k_conv_h(
    const u16* __restrict__ WHB, const u16* __restrict__ XtH,
    const float* __restrict__ bh, u16* Hb) {
    int bidn = blockIdx.x & 255, bido = blockIdx.x >> 8;
    int w = threadIdx.x >> 6, lane = threadIdx.x & 63, r = lane & 15, g = lane >> 4;
    int o0 = bido * 64 + w * 16, n0 = bidn * 64;
    f32x4 acc[4];
#pragma unroll
    for (int i = 0; i < 4; ++i) acc[i] = {0.f, 0.f, 0.f, 0.f};
    const u16* arow = WHB + (size_t)(o0 + r) * 256;
#pragma unroll
    for (int ks = 0; ks < 8; ++ks) {
        int k0 = ks * 32 + 8 * g;
        short8 a = ld8(arow + k0);
#pragma unroll
        for (int ntl = 0; ntl < 4; ++ntl) {
            short8 bb = ld8(XtH + (size_t)(n0 + ntl * 16 + r) * 256 + k0);
            acc[ntl] = MFMA(a, bb, acc[ntl]);
        }
    }
#pragma unroll
    for (int ntl = 0; ntl < 4; ++ntl) {
#pragma unroll
        for (int q = 0; q < 4; ++q) {
            int o = o0 + 4 * g + q;
            int nf = n0 + ntl * 16 + r;
            int bb = nf >> 12, n = nf & 4095;
            // permute key within its 32-block: slot kinv(k) holds key k, so the
            // attention PV B-fragment (slots 8g+j) is lane-local after swapped QK.
            int k5 = n & 31;
            int kp = (k5 < 16) ? (8 * (k5 >> 2) + (k5 & 3))
                               : (8 * ((k5 - 16) >> 2) + 4 + (k5 & 3));
            int np = (n & ~31) | kp;
            Hb[((size_t)(bb * 256 + o)) * 4096 + np] = h16(acc[ntl][q] + bh[o]);
        }
    }
}

// ---------------- flash attention: swapped-QK 16x16, lane-local P, shfl softmax ----------------
__global__ __launch_bounds__(256, 2) void k_attn(
    const u16* __restrict__ F, const u16* __restrict__ G,
    const u16* __restrict__ Hb, u16* __restrict__ OP, float* __restrict__ ML) {
    // K tile [32 keys][256 c] fp16, 16KB each, swizzle byte ^= (row&7)<<4.
    // V tile paired-row: byte(c,s) = (c>>1)*128 + ((s*2 + (c&1)*64) ^ (((c>>1)&7)<<4)),
    // where slot s holds key kappa(s) (permutation baked into H by conv_h).
    __shared__ u16 Kd[2][8192];
    __shared__ u16 Vd[2][8192];

    int bid = blockIdx.x;            // 512 = 8 xcd * 64; 2 blocks/CU
    int xcd = bid & 7, idx = bid >> 3;
    int b = xcd >> 1, ks = xcd & 1;  // XCD carries (batch, key-half)
    int tid = threadIdx.x;
    int w = tid >> 6, lane = tid & 63, r = lane & 15, g = lane >> 4;
    int j0 = idx * 64 + w * 16;      // wave's 16 queries
    const float L2E = 1.4426950408889634f;

    // Q as QK B-operand (col = query r): Qf[k] = Q[j0+r][k*32 + 8g .. +7]
    f16x8 Qf[8];
    {
        const u16* q = G + (size_t)(b * 4096 + j0 + r) * 256;
#pragma unroll
        for (int k = 0; k < 8; ++k) Qf[k] = ldh8(q + k * 32 + 8 * g);
    }
    // O[ct][q] = O[channel ct*16 + 4g + q][query j0 + r]  (PV D-layout, col = query)
    f32x4 O[16];
#pragma unroll
    for (int i = 0; i < 16; ++i) O[i] = {0.f, 0.f, 0.f, 0.f};
    float m = -1e30f, l = 0.f;       // per-query (lane-scalar)

    const char* Fb  = (const char*)(F + (size_t)b * 4096 * 256);
    const char* Hbb = (const char*)(Hb + (size_t)b * 256 * 4096);

    // per-lane pre-swizzled stage source offsets (dest is linear)
    int ksrc[4], vsrc[4];
#pragma unroll
    for (int t = 0; t < 4; ++t) {
        int d = (w * 4 + t) * 1024 + lane * 16;
        int row = d >> 9, col = d & 511;
        ksrc[t] = row * 512 + (col ^ ((row & 7) << 4));
        int r128 = d >> 7, wn = d & 127;
        int wp = wn ^ ((r128 & 7) << 4);
        vsrc[t] = ((r128 * 2 + (wp >> 6)) << 13) + (wp & 63);
    }

#define STAGE(bufn, I0)                                                         \
    do {                                                                        \
        const char* kb_ = Fb + (size_t)(I0) * 512;                              \
        const char* vb_ = Hbb + (size_t)(I0) * 2;                               \
        char* kl = (char*)Kd[bufn];                                             \
        char* vl = (char*)Vd[bufn];                                             \
        _Pragma("unroll") for (int t = 0; t < 4; ++t)                           \
            gload16(kb_ + ksrc[t], kl + (w * 4 + t) * 1024);                    \
        _Pragma("unroll") for (int t = 0; t < 4; ++t)                           \
            gload16(vb_ + vsrc[t], vl + (w * 4 + t) * 1024);                    \
    } while (0)

    int i0beg = ks * 2048;
    STAGE(0, i0beg);   // prologue
    __syncthreads();   // drains vmcnt(0): tile 0 ready

    for (int it = 0; it < 64; ++it) {
        int cur = it & 1;
        if (it + 1 < 64) STAGE(cur ^ 1, i0beg + (it + 1) * 32);  // fly under compute

        const char* Kl = (const char*)Kd[cur];
        const char* Vl = (const char*)Vd[cur];

        // ---- QK^T swapped: A = K (rows = keys), B = Q. Reads identical to r8.
        // s0[q] = S[key 4g+q][query r], s1[q] = S[key 16+4g+q][query r]
        f32x4 s0 = {0.f, 0.f, 0.f, 0.f};
        f32x4 s1 = {0.f, 0.f, 0.f, 0.f};
        __builtin_amdgcn_s_setprio(1);
        {
            const char* kr = Kl + r * 512;
            int sw = (r & 7) << 4;
#pragma unroll
            for (int k = 0; k < 8; ++k) {
                f16x8 ka = *reinterpret_cast<const f16x8*>(kr + ((k * 64 + 16 * g) ^ sw));
                s0 = MFMA16(ka, Qf[k], s0);
            }
        }
        {
            const char* kr = Kl + (16 + r) * 512;
            int sw = (r & 7) << 4;  // (16+r)&7 == r&7
#pragma unroll
            for (int k = 0; k < 8; ++k) {
                f16x8 ka = *reinterpret_cast<const f16x8*>(kr + ((k * 64 + 16 * g) ^ sw));
                s1 = MFMA16(ka, Qf[k], s1);
            }
        }
        __builtin_amdgcn_s_setprio(0);

        // ---- softmax: lane holds 8 scores of query r; reduce over g-lanes via shfl ----
        float v = fmaxf(fmaxf(fmaxf(s0[0], s0[1]), fmaxf(s0[2], s0[3])),
                        fmaxf(fmaxf(s1[0], s1[1]), fmaxf(s1[2], s1[3])));
        v = fmaxf(v, __shfl_xor(v, 16));
        v = fmaxf(v, __shfl_xor(v, 32));
        float grow = v - m;
        if (__all(grow <= 8.0f)) {  // T13 defer-max: skip rescale
#pragma unroll
            for (int q = 0; q < 4; ++q) {
                s0[q] = exp2f((s0[q] - m) * L2E);
                s1[q] = exp2f((s1[q] - m) * L2E);
            }
            float rs = (s0[0] + s0[1] + s0[2] + s0[3]) + (s1[0] + s1[1] + s1[2] + s1[3]);
            rs += __shfl_xor(rs, 16);
            rs += __shfl_xor(rs, 32);
            l += rs;
        } else {
            float mn = fmaxf(m, v);
            float corr = exp2f((m - mn) * L2E);
            m = mn;
#pragma unroll
            for (int q = 0; q < 4; ++q) {
                s0[q] = exp2f((s0[q] - m) * L2E);
                s1[q] = exp2f((s1[q] - m) * L2E);
            }
            float rs = (s0[0] + s0[1] + s0[2] + s0[3]) + (s1[0] + s1[1] + s1[2] + s1[3]);
            rs += __shfl_xor(rs, 16);
            rs += __shfl_xor(rs, 32);
            l = l * corr + rs;
#pragma unroll
            for (int ct = 0; ct < 16; ++ct) O[ct] *= corr;  // whole lane = one query
        }

        // ---- P -> PV B-frag: LANE-LOCAL (V keys permuted so slot 8g+j = key kappa) ----
        union { u32 wd[4]; f16x8 fr; } pu;
        pu.wd[0] = cvtpk(s0[0], s0[1]);
        pu.wd[1] = cvtpk(s0[2], s0[3]);
        pu.wd[2] = cvtpk(s1[0], s1[1]);
        pu.wd[3] = cvtpk(s1[2], s1[3]);

        // ---- PV: O[c][j] += V[c][slot] * P[slot][j]; A = V (reads identical to r8) ----
        __builtin_amdgcn_s_setprio(1);
#pragma unroll
        for (int ct = 0; ct < 16; ++ct) {
            int c = ct * 16 + r;
            const char* vr = Vl + (c >> 1) * 128;
            int swv = ((c >> 1) & 7) << 4;
            int cb = (c & 1) * 64;
            f16x8 vb = *reinterpret_cast<const f16x8*>(vr + ((16 * g + cb) ^ swv));
            O[ct] = MFMA16(vb, pu.fr, O[ct]);
        }
        __builtin_amdgcn_s_setprio(0);

        __syncthreads();  // drains vmcnt (next tile landed during compute); buffer reuse safe
    }
#undef STAGE

    // ---- normalize (lane-scalar) + packed store: O[ct][q] -> channel ct*16+4g+q ----
    float inv = 1.f / l;
    size_t mrow = (size_t)ks * 16384 + b * 4096 + j0 + r;
#pragma unroll
    for (int ct = 0; ct < 16; ++ct) {
        short4v pk;
#pragma unroll
        for (int q = 0; q < 4; ++q) pk[q] = (short)h16(O[ct][q] * inv);
        *reinterpret_cast<short4v*>(OP + mrow * 256 + ct * 16 + 4 * g) = pk;
    }
    if (g == 0) {
        size_t mi = mrow * 2;
        ML[mi] = m;
        ML[mi + 1] = l;
    }
}

// ---------------- merge key-splits (x2, normalized partials) -> OT fp16 [m][c] ----------------
__global__ __launch_bounds__(256) void k_merge(
    const u16* __restrict__ OP, const float* __restrict__ ML, u16* __restrict__ OT) {
    int t = blockIdx.x * 256 + threadIdx.x;  // 524288 threads
    int m = t >> 5;
    int c0 = (t & 31) * 8;
    const float L2E = 1.4426950408889634f;
    float m0 = ML[(size_t)m * 2], l0 = ML[(size_t)m * 2 + 1];
    float m1 = ML[((size_t)16384 + m) * 2], l1 = ML[((size_t)16384 + m) * 2 + 1];
    float M = fmaxf(m0, m1);
    float wl0 = exp2f((m0 - M) * L2E) * l0;
    float wl1 = exp2f((m1 - M) * L2E) * l1;
    float inv = 1.f / (wl0 + wl1);
    f16x8 v0 = ldh8(OP + (size_t)m * 256 + c0);
    f16x8 v1 = ldh8(OP + ((size_t)16384 + m) * 256 + c0);
    short8 outp;
#pragma unroll
    for (int j = 0; j < 8; ++j)
        outp[j] = (short)h16((wl0 * (float)v0[j] + wl1 * (float)v1[j]) * inv);
    *reinterpret_cast<short8*>(OT + (size_t)m * 256 + c0) = outp;
}

// ---------------- final conv: fp16 MFMA, f32 out ----------------
__global__ __launch_bounds__(256) void k_conv_out(
    const u16* __restrict__ WVB, const u16* __restrict__ OT,
    const float* __restrict__ bv, float* __restrict__ out) {
    int bidn = blockIdx.x & 255, bido = blockIdx.x >> 8;
    int w = threadIdx.x >> 6, lane = threadIdx.x & 63, r = lane & 15, g = lane >> 4;
    int o0 = bido * 64 + w * 16, n0 = bidn * 64;
    f32x4 acc[4];
#pragma unroll
    for (int i = 0; i < 4; ++i) acc[i] = {0.f, 0.f, 0.f, 0.f};
    const u16* arow = WVB + (size_t)(o0 + r) * 256;
#pragma unroll
    for (int ks = 0; ks < 8; ++ks) {
        int k0 = ks * 32 + 8 * g;
        f16x8 a = ldh8(arow + k0);
#pragma unroll
        for (int ntl = 0; ntl < 4; ++ntl) {
            f16x8 bb = ldh8(OT + (size_t)(n0 + ntl * 16 + r) * 256 + k0);
            acc[ntl] = MFMA16(a, bb, acc[ntl]);
        }
    }
#pragma unroll
    for (int ntl = 0; ntl < 4; ++ntl) {
#pragma unroll
        for (int q = 0; q < 4; ++q) {
            int o = o0 + 4 * g + q;
            int nf = n0 + ntl * 16 + r;
            int bb = nf >> 12, n = nf & 4095;
            out[((size_t)(bb * 256 + o)) * 4096 + n] = acc[ntl][q] + bv[o];
        }
    }
}

extern "C" void kernel_launch(void* const* d_in, const int* in_sizes, int n_in,
                              void* d_out, int out_size, void* d_ws, size_t ws_size,
                              hipStream_t stream) {
    const float* x  = (const float*)d_in[0];
    const float* Wf = (const float*)d_in[1];
    const float* bf = (const float*)d_in[2];
    const float* Wg = (const float*)d_in[3];
    const float* bg = (const float*)d_in[4];
    const float* Wh = (const float*)d_in[5];
    const float* bh = (const float*)d_in[6];
    const float* Wv = (const float*)d_in[7];
    const float* bv = (const float*)d_in[8];
    float* out = (float*)d_out;
    char* ws = (char*)d_ws;

    u16* WFH = (u16*)(ws + OFF_WFH);
    u16* WFL = (u16*)(ws + OFF_WFL);
    u16* WGH = (u16*)(ws + OFF_WGH);
    u16* WGL = (u16*)(ws + OFF_WGL);
    u16* WHB = (u16*)(ws + OFF_WHB);
    u16* WVB = (u16*)(ws + OFF_WVB);
    float* ML = (float*)(ws + OFF_ML);
    u16* F   = (u16*)(ws + OFF_F);
    u16* G   = (u16*)(ws + OFF_G);
    u16* H   = (u16*)(ws + OFF_H);
    u16* XTH = (u16*)(ws + OFF_XTH);
    u16* XTL = (u16*)(ws + OFF_XTL);
    u16* OP  = (u16*)(ws + OFF_OP);   // aliases Xt (dead after convs)
    u16* OT  = (u16*)(ws + OFF_OT);   // aliases F (dead after attn)

    k_prep_w<<<256, 256, 0, stream>>>(Wf, Wg, Wh, Wv, WFH, WFL, WGH, WGL, WHB, WVB);
    k_prep_x<<<1024, 256, 0, stream>>>(x, XTH, XTL);
    k_conv_fg<<<1024, 256, 0, stream>>>(XTH, XTL, WFH, WFL, WGH, WGL, bf, bg, F, G);
    k_conv_h<<<1024, 256, 0, stream>>>(WHB, XTH, bh, H);
    k_attn<<<512, 256, 0, stream>>>(F, G, H, OP, ML);
    k_merge<<<2048, 256, 0, stream>>>(OP, ML, OT);
    k_conv_out<<<1024, 256, 0, stream>>>(WVB, OT, bv, out);
}